// Round 2
// baseline (2940.699 us; speedup 1.0000x reference)
//
#include <hip/hip_runtime.h>
#include <hip/hip_bf16.h>

// ---------------------------------------------------------------------------
// FourDNet forward, fp32 compute, bf16 conv intermediates.
// B=64, N=128, RED=128, MK=24, HD=32, WD=16.
// d_out layout: [cls_score 64*751][final_embedding 64*128], fp32.
// ---------------------------------------------------------------------------

#define TS 64
#define KS 16

// Generic tiled GEMM: C[M,N] = A[M,K] @ B[K,N] (+bias)
// a_mode: 0 identity rows, 1 features-local rows (m + (m>>7) + 1), 2 features-global rows (m*129)
// bias_mode: 0 none, 1 per-col bias[N], 2 per-row-block bias[(m>>7)*N + n]
__global__ __launch_bounds__(256) void gemm_f32(
    const float* __restrict__ A, const float* __restrict__ B,
    const float* __restrict__ bias, float* __restrict__ C,
    int M, int N, int K, int lda, int ldb, int ldc,
    int a_mode, int bias_mode)
{
    __shared__ float As[KS][TS + 1];   // [k][m], padded
    __shared__ float Bs[KS][TS + 4];   // [k][n], padded
    int tid = threadIdx.x;
    int tx = tid & 15, ty = tid >> 4;
    int n0 = blockIdx.x * TS;
    int m0 = blockIdx.y * TS;
    float acc[4][4] = {};

    int a_k = tid & 15;   // k within tile
    int a_m = tid >> 4;   // 16 rows per pass
    int b_n = tid & 63;
    int b_k = tid >> 6;   // 4 k per pass

    for (int k0 = 0; k0 < K; k0 += KS) {
#pragma unroll
        for (int p = 0; p < 4; ++p) {
            int m = a_m + p * 16;
            int gm = m0 + m;
            int pr = (a_mode == 1) ? (gm + (gm >> 7) + 1)
                    : (a_mode == 2) ? (gm * 129) : gm;
            As[a_k][m] = A[(long)pr * lda + k0 + a_k];
        }
#pragma unroll
        for (int p = 0; p < 4; ++p) {
            int k = b_k + p * 4;
            int gn = n0 + b_n;
            Bs[k][b_n] = (gn < N) ? B[(long)(k0 + k) * ldb + gn] : 0.f;
        }
        __syncthreads();
#pragma unroll
        for (int k = 0; k < KS; ++k) {
            float a[4], b[4];
#pragma unroll
            for (int i = 0; i < 4; ++i) a[i] = As[k][ty * 4 + i];
#pragma unroll
            for (int j = 0; j < 4; ++j) b[j] = Bs[k][tx * 4 + j];
#pragma unroll
            for (int i = 0; i < 4; ++i)
#pragma unroll
                for (int j = 0; j < 4; ++j)
                    acc[i][j] = fmaf(a[i], b[j], acc[i][j]);
        }
        __syncthreads();
    }
#pragma unroll
    for (int i = 0; i < 4; ++i) {
        int m = m0 + ty * 4 + i;
#pragma unroll
        for (int j = 0; j < 4; ++j) {
            int n = n0 + tx * 4 + j;
            if (n < N) {
                float v = acc[i][j];
                if (bias_mode == 1) v += bias[n];
                else if (bias_mode == 2) v += bias[(m >> 7) * N + n];
                C[(long)m * ldc + n] = v;
            }
        }
    }
}

// conv1: d (64,1,256,128) f32 -> out (64,64,128,64) bf16. stride2 pad1 3x3.
__global__ __launch_bounds__(256) void conv1_k(
    const float* __restrict__ d, const float* __restrict__ w,
    const float* __restrict__ bias, __hip_bfloat16* __restrict__ out)
{
    int idx = blockIdx.x * 256 + threadIdx.x;   // ((b*64+oc)*128+oh)*64+ow
    int ow = idx & 63;
    int oh = (idx >> 6) & 127;
    int oc = (idx >> 13) & 63;
    int b  = idx >> 19;
    float acc = bias[oc];
#pragma unroll
    for (int kh = 0; kh < 3; ++kh) {
        int ih = oh * 2 - 1 + kh;
        if (ih < 0 || ih >= 256) continue;
#pragma unroll
        for (int kw = 0; kw < 3; ++kw) {
            int iw = ow * 2 - 1 + kw;
            if (iw < 0 || iw >= 128) continue;
            acc = fmaf(d[(b * 256 + ih) * 128 + iw], w[oc * 9 + kh * 3 + kw], acc);
        }
    }
    out[idx] = __float2bfloat16(acc);
}

// conv2: in (64,64,128,64) bf16 -> out (64,128,64,32) bf16
__global__ __launch_bounds__(256) void conv2_k(
    const __hip_bfloat16* __restrict__ in, const float* __restrict__ w,
    const float* __restrict__ bias, __hip_bfloat16* __restrict__ out)
{
    __shared__ __hip_bfloat16 ins[3][64][66];   // halo: iwp = iw+1
    __shared__ float ws[8 * 577];               // padded per-oc rows
    int tid = threadIdx.x;
    int oc0 = blockIdx.x * 8;
    int oh  = blockIdx.y;
    int b   = blockIdx.z;

    for (int l = tid; l < 3 * 64 * 66; l += 256) {
        int iwp = l % 66;
        int ic  = (l / 66) % 64;
        int r   = l / (66 * 64);
        int ih = oh * 2 - 1 + r;
        int iw = iwp - 1;
        __hip_bfloat16 hv = __float2bfloat16(0.f);
        if (ih >= 0 && ih < 128 && iw >= 0 && iw < 64)
            hv = in[((b * 64 + ic) * 128 + ih) * 64 + iw];
        ins[r][ic][iwp] = hv;
    }
    for (int l = tid; l < 8 * 576; l += 256) {
        int ocl = l / 576;
        ws[ocl * 577 + (l % 576)] = w[oc0 * 576 + l];
    }
    __syncthreads();

    int ow  = tid & 31;
    int ocl = tid >> 5;
    float acc = bias[oc0 + ocl];
    const float* wp = &ws[ocl * 577];
    for (int ic = 0; ic < 64; ++ic) {
#pragma unroll
        for (int kh = 0; kh < 3; ++kh)
#pragma unroll
            for (int kw = 0; kw < 3; ++kw)
                acc = fmaf(__bfloat162float(ins[kh][ic][2 * ow + kw]),
                           wp[ic * 9 + kh * 3 + kw], acc);
    }
    out[((b * 128 + oc0 + ocl) * 64 + oh) * 32 + ow] = __float2bfloat16(acc);
}

// conv3: in (64,128,64,32) bf16 -> dep (64, 512=hw, 128=oc) f32 (transposed out)
__global__ __launch_bounds__(256) void conv3_k(
    const __hip_bfloat16* __restrict__ in, const float* __restrict__ w,
    const float* __restrict__ bias, float* __restrict__ dep)
{
    __shared__ __hip_bfloat16 ins[3][32][34];
    __shared__ float ws[16 * 289];
    int tid = threadIdx.x;
    int oc0 = blockIdx.x * 16;
    int oh  = blockIdx.y;   // 0..31
    int b   = blockIdx.z;
    int ocl = tid & 15;
    int ow  = tid >> 4;     // 0..15
    float acc = bias[oc0 + ocl];

    for (int c0 = 0; c0 < 128; c0 += 32) {
        __syncthreads();
        for (int l = tid; l < 3 * 32 * 34; l += 256) {
            int iwp = l % 34;
            int ic  = (l / 34) % 32;
            int r   = l / (34 * 32);
            int ih = oh * 2 - 1 + r;
            int iw = iwp - 1;
            __hip_bfloat16 hv = __float2bfloat16(0.f);
            if (ih >= 0 && ih < 64 && iw >= 0 && iw < 32)
                hv = in[((b * 128 + c0 + ic) * 64 + ih) * 32 + iw];
            ins[r][ic][iwp] = hv;
        }
        for (int l = tid; l < 16 * 288; l += 256) {
            int o = l / 288;
            ws[o * 289 + (l % 288)] = w[(oc0 + o) * 1152 + c0 * 9 + (l % 288)];
        }
        __syncthreads();
        const float* wp = &ws[ocl * 289];
        for (int ic = 0; ic < 32; ++ic) {
#pragma unroll
            for (int kh = 0; kh < 3; ++kh)
#pragma unroll
                for (int kw = 0; kw < 3; ++kw)
                    acc = fmaf(__bfloat162float(ins[kh][ic][2 * ow + kw]),
                               wp[ic * 9 + kh * 3 + kw], acc);
        }
    }
    dep[(b * 512 + oh * 16 + ow) * 128 + oc0 + ocl] = acc;
}

// c0[j] = g_depth @ W_merge[0:128] + b_merge
__global__ void c0_k(const float* __restrict__ g_depth, const float* __restrict__ Wm,
                     const float* __restrict__ bm, float* __restrict__ c0)
{
    int j = threadIdx.x;   // 128
    float acc = bm[j];
    for (int k = 0; k < 128; ++k) acc = fmaf(g_depth[k], Wm[k * 128 + j], acc);
    c0[j] = acc;
}

// sel postprocess: sigmoid + slice + softmax(attn)
__global__ __launch_bounds__(64) void sel_post_k(
    const float* __restrict__ raw, float* __restrict__ lx,
    float* __restrict__ ly, float* __restrict__ attn)
{
    int row = blockIdx.x;
    int t = threadIdx.x;
    __shared__ float a_s[24];
    __shared__ float red[2];
    const float* r = raw + row * 72;
    float lxv = 0.f, lyv = 0.f;
    if (t < 24) {
        lxv = 1.f / (1.f + expf(-r[2 * t]));
        lyv = 1.f / (1.f + expf(-r[2 * t + 1]));
        a_s[t] = 1.f / (1.f + expf(-r[48 + t]));
    }
    __syncthreads();
    if (t == 0) {
        float mx = a_s[0];
        for (int k = 1; k < 24; ++k) mx = fmaxf(mx, a_s[k]);
        float s = 0.f;
        for (int k = 0; k < 24; ++k) s += expf(a_s[k] - mx);
        red[0] = mx; red[1] = s;
    }
    __syncthreads();
    if (t < 24) {
        lx[row * 24 + t] = lxv;
        ly[row * 24 + t] = lyv;
        attn[row * 24 + t] = expf(a_s[t] - red[0]) / red[1];
    }
}

// bilinear gather + attn-weighted mean over 24 keypoints
__global__ __launch_bounds__(128) void r2d_k(
    const float* __restrict__ v, const float* __restrict__ lx,
    const float* __restrict__ ly, const float* __restrict__ attn,
    float* __restrict__ r2d)
{
    int n = blockIdx.x;   // 0..127
    int b = blockIdx.y;
    int c = threadIdx.x;  // 0..127
    int row = b * 128 + n;
    __shared__ float sx[24], sy[24], sa[24];
    if (c < 24) { sx[c] = lx[row * 24 + c]; sy[c] = ly[row * 24 + c]; sa[c] = attn[row * 24 + c]; }
    __syncthreads();
    const float* vb = v + (long)b * 512 * 128;
    float acc = 0.f;
    for (int k = 0; k < 24; ++k) {
        float lxv = sx[k], lyv = sy[k], a = sa[k];
        float x1 = floorf(lxv * 15.f), x2 = fminf(x1 + 1.f, 15.f);
        float y1 = floorf(lyv * 31.f), y2 = fminf(y1 + 1.f, 31.f);
        int xi1 = (int)x1, xi2 = (int)x2, yi1 = (int)y1, yi2 = (int)y2;
        float f0 = vb[(xi1 * 16 + yi2) * 128 + c];
        float f1 = vb[(xi2 * 16 + yi2) * 128 + c];
        float f2 = vb[(xi2 * 16 + yi1) * 128 + c];
        float f3 = vb[(xi1 * 16 + yi1) * 128 + c];
        float x = lxv * 16.f, y = lyv * 32.f;
        float w_ = x2 - x1, h_ = y2 - y1;
        float hwp = h_ * w_;
        bool deg = (h_ == 0.f) || (w_ == 0.f);
        float denom = (hwp == 0.f) ? 1.f : hwp;
        float coeff = deg ? 2.f : 1.f / denom;
        float xv0 = (w_ == 0.f) ? 1.f : (x2 - x);
        float xv1 = (w_ == 0.f) ? 1.f : (x - x1);
        float yv0 = (h_ == 0.f) ? 1.f : (y2 - y);
        float yv1 = (h_ == 0.f) ? 1.f : (y - y1);
        float interp = coeff * (xv0 * (f0 * yv0 + f1 * yv1) + xv1 * (f2 * yv0 + f3 * yv1));
        acc = fmaf(interp, a, acc);
    }
    r2d[(long)row * 128 + c] = acc * (1.f / 24.f);
}

// final_embedding[b,c] = mean over n of r2d
__global__ __launch_bounds__(128) void fe_k(const float* __restrict__ r2d,
                                            float* __restrict__ fe)
{
    int b = blockIdx.x;
    int c = threadIdx.x;
    float acc = 0.f;
    for (int nn = 0; nn < 128; ++nn) acc += r2d[((long)b * 128 + nn) * 128 + c];
    fe[b * 128 + c] = acc * (1.f / 128.f);
}

extern "C" void kernel_launch(void* const* d_in, const int* in_sizes, int n_in,
                              void* d_out, int out_size, void* d_ws, size_t ws_size,
                              hipStream_t stream)
{
    const float* features = (const float*)d_in[0];
    const float* d        = (const float*)d_in[1];
    const float* W_rg  = (const float*)d_in[2];
    const float* b_rg  = (const float*)d_in[3];
    const float* W_rl  = (const float*)d_in[4];
    const float* b_rl  = (const float*)d_in[5];
    const float* c1w   = (const float*)d_in[6];
    const float* c1b   = (const float*)d_in[7];
    const float* c2w   = (const float*)d_in[8];
    const float* c2b   = (const float*)d_in[9];
    const float* c3w   = (const float*)d_in[10];
    const float* c3b   = (const float*)d_in[11];
    const float* g_depth = (const float*)d_in[12];
    const float* W_merge = (const float*)d_in[13];
    const float* b_merge = (const float*)d_in[14];
    const float* W_q   = (const float*)d_in[15];
    const float* b_q   = (const float*)d_in[16];
    const float* W_v   = (const float*)d_in[17];
    const float* b_v   = (const float*)d_in[18];
    const float* W_sel = (const float*)d_in[19];
    const float* b_sel = (const float*)d_in[20];
    const float* W_cls = (const float*)d_in[21];
    float* out = (float*)d_out;

    char* ws = (char*)d_ws;
    // Overlaid layout (c1 region reused by dep/merged/v after conv2):
    __hip_bfloat16* c1 = (__hip_bfloat16*)(ws + 0);            // 67,108,864 B
    float* dep    = (float*)(ws + 0);                          // 16,777,216 (after c1 dead)
    float* merged = (float*)(ws + 16777216);                   // 16,777,216
    float* v      = (float*)(ws + 33554432);                   // 16,777,216
    __hip_bfloat16* c2 = (__hip_bfloat16*)(ws + 67108864);     // 33,554,432
    float* lfeat  = (float*)(ws + 100663296);                  // 4,194,304
    float* q      = (float*)(ws + 104857600);                  // 4,194,304
    float* selraw = (float*)(ws + 109051904);                  // 2,359,296
    float* lxb    = (float*)(ws + 111411200);                  // 786,432
    float* lyb    = (float*)(ws + 112197632);                  // 786,432
    float* attnb  = (float*)(ws + 112984064);                  // 786,432
    float* gfeat  = (float*)(ws + 113770496);                  // 32,768
    float* gq     = (float*)(ws + 113803264);                  // 32,768
    float* c0b    = (float*)(ws + 113836032);                  // 512
    float* r2d    = (float*)(ws + 113836544);                  // 4,194,304  (end ~112.6 MB)

    float* fe = out + 64 * 751;

    // ---- conv path ----
    conv1_k<<<131072, 256, 0, stream>>>(d, c1w, c1b, c1);
    conv2_k<<<dim3(16, 64, 64), 256, 0, stream>>>(c1, c2w, c2b, c2);
    conv3_k<<<dim3(8, 32, 64), 256, 0, stream>>>(c2, c3w, c3b, dep);
    c0_k<<<1, 128, 0, stream>>>(g_depth, W_merge, b_merge, c0b);
    // merged = dep @ W_merge[128:] + c0
    gemm_f32<<<dim3(2, 512), 256, 0, stream>>>(dep, W_merge + 128 * 128, c0b, merged,
                                               32768, 128, 128, 128, 128, 128, 0, 1);
    // v = merged @ W_v + b_v
    gemm_f32<<<dim3(2, 512), 256, 0, stream>>>(merged, W_v, b_v, v,
                                               32768, 128, 128, 128, 128, 128, 0, 1);

    // ---- feature path ----
    // global_feat = features[:,0] @ W_rg + b_rg
    gemm_f32<<<dim3(2, 1), 256, 0, stream>>>(features, W_rg, b_rg, gfeat,
                                             64, 128, 768, 768, 128, 128, 2, 1);
    // gq = global_feat @ W_q[0:128] + b_q
    gemm_f32<<<dim3(2, 1), 256, 0, stream>>>(gfeat, W_q, b_q, gq,
                                             64, 128, 128, 128, 128, 128, 0, 1);
    // local_feat = features[:,1:] @ W_rl + b_rl
    gemm_f32<<<dim3(2, 128), 256, 0, stream>>>(features, W_rl, b_rl, lfeat,
                                               8192, 128, 768, 768, 128, 128, 1, 1);
    // q = local_feat @ W_q[128:] + gq[b]
    gemm_f32<<<dim3(2, 128), 256, 0, stream>>>(lfeat, W_q + 128 * 128, gq, q,
                                               8192, 128, 128, 128, 128, 128, 0, 2);
    // selraw = q @ W_sel + b_sel
    gemm_f32<<<dim3(2, 128), 256, 0, stream>>>(q, W_sel, b_sel, selraw,
                                               8192, 72, 128, 128, 72, 72, 0, 1);
    sel_post_k<<<8192, 64, 0, stream>>>(selraw, lxb, lyb, attnb);

    // ---- fusion tail ----
    r2d_k<<<dim3(128, 64), 128, 0, stream>>>(v, lxb, lyb, attnb, r2d);
    fe_k<<<64, 128, 0, stream>>>(r2d, fe);
    // cls = fe @ W_cls
    gemm_f32<<<dim3(12, 1), 256, 0, stream>>>(fe, W_cls, nullptr, out,
                                              64, 751, 128, 128, 751, 751, 0, 0);
}

// Round 3
// 624.728 us; speedup vs baseline: 4.7072x; 4.7072x over previous
//
#include <hip/hip_runtime.h>
#include <hip/hip_bf16.h>

// ---------------------------------------------------------------------------
// FourDNet forward. Convs = bf16 MFMA implicit GEMM (NHWC), GEMM chain fp32.
// B=64, N=128, RED=128, MK=24, HD=32, WD=16.
// d_out layout: [cls_score 64*751][final_embedding 64*128], fp32.
// ---------------------------------------------------------------------------

typedef __attribute__((ext_vector_type(8))) short short8;
typedef __attribute__((ext_vector_type(4))) float floatx4;

#define TS 64
#define KS 16

// Generic tiled GEMM: C[M,N] = A[M,K] @ B[K,N] (+bias)
// a_mode: 0 identity rows, 1 features-local rows (m + (m>>7) + 1), 2 features-global rows (m*129)
// bias_mode: 0 none, 1 per-col bias[N], 2 per-row-block bias[(m>>7)*N + n]
__global__ __launch_bounds__(256) void gemm_f32(
    const float* __restrict__ A, const float* __restrict__ B,
    const float* __restrict__ bias, float* __restrict__ C,
    int M, int N, int K, int lda, int ldb, int ldc,
    int a_mode, int bias_mode)
{
    __shared__ float As[KS][TS + 1];
    __shared__ float Bs[KS][TS + 4];
    int tid = threadIdx.x;
    int tx = tid & 15, ty = tid >> 4;
    int n0 = blockIdx.x * TS;
    int m0 = blockIdx.y * TS;
    float acc[4][4] = {};

    int a_k = tid & 15;
    int a_m = tid >> 4;
    int b_n = tid & 63;
    int b_k = tid >> 6;

    for (int k0 = 0; k0 < K; k0 += KS) {
#pragma unroll
        for (int p = 0; p < 4; ++p) {
            int m = a_m + p * 16;
            int gm = m0 + m;
            int pr = (a_mode == 1) ? (gm + (gm >> 7) + 1)
                    : (a_mode == 2) ? (gm * 129) : gm;
            As[a_k][m] = A[(long)pr * lda + k0 + a_k];
        }
#pragma unroll
        for (int p = 0; p < 4; ++p) {
            int k = b_k + p * 4;
            int gn = n0 + b_n;
            Bs[k][b_n] = (gn < N) ? B[(long)(k0 + k) * ldb + gn] : 0.f;
        }
        __syncthreads();
#pragma unroll
        for (int k = 0; k < KS; ++k) {
            float a[4], b[4];
#pragma unroll
            for (int i = 0; i < 4; ++i) a[i] = As[k][ty * 4 + i];
#pragma unroll
            for (int j = 0; j < 4; ++j) b[j] = Bs[k][tx * 4 + j];
#pragma unroll
            for (int i = 0; i < 4; ++i)
#pragma unroll
                for (int j = 0; j < 4; ++j)
                    acc[i][j] = fmaf(a[i], b[j], acc[i][j]);
        }
        __syncthreads();
    }
#pragma unroll
    for (int i = 0; i < 4; ++i) {
        int m = m0 + ty * 4 + i;
#pragma unroll
        for (int j = 0; j < 4; ++j) {
            int n = n0 + tx * 4 + j;
            if (n < N) {
                float v = acc[i][j];
                if (bias_mode == 1) v += bias[n];
                else if (bias_mode == 2) v += bias[(m >> 7) * N + n];
                C[(long)m * ldc + n] = v;
            }
        }
    }
}

// weight transform: OIHW fp32 -> [oc][(kh*3+kw)*IC + ic] bf16
__global__ __launch_bounds__(256) void wt2_k(const float* __restrict__ w,
                                             __hip_bfloat16* __restrict__ wt)
{
    int idx = blockIdx.x * 256 + threadIdx.x;     // 128*576
    if (idx >= 128 * 576) return;
    int oc = idx / 576, k = idx % 576;
    int s = k >> 6, ic = k & 63;
    wt[idx] = __float2bfloat16(w[oc * 576 + ic * 9 + s]);
}
__global__ __launch_bounds__(256) void wt3_k(const float* __restrict__ w,
                                             __hip_bfloat16* __restrict__ wt)
{
    int idx = blockIdx.x * 256 + threadIdx.x;     // 128*1152
    if (idx >= 128 * 1152) return;
    int oc = idx / 1152, k = idx % 1152;
    int s = k >> 7, ic = k & 127;
    wt[idx] = __float2bfloat16(w[oc * 1152 + ic * 9 + s]);
}

// conv1: d (64,1,256,128) f32 -> out NHWC (64,128,64,64) bf16. stride2 pad1 3x3.
__global__ __launch_bounds__(256) void conv1_k(
    const float* __restrict__ d, const float* __restrict__ w,
    const float* __restrict__ bias, __hip_bfloat16* __restrict__ out)
{
    int idx = blockIdx.x * 256 + threadIdx.x;   // ((b*128+oh)*64+ow)*64+oc
    int oc = idx & 63;
    int ow = (idx >> 6) & 63;
    int oh = (idx >> 12) & 127;
    int b  = idx >> 19;
    float acc = bias[oc];
#pragma unroll
    for (int kh = 0; kh < 3; ++kh) {
        int ih = oh * 2 - 1 + kh;
        if (ih < 0 || ih >= 256) continue;
#pragma unroll
        for (int kw = 0; kw < 3; ++kw) {
            int iw = ow * 2 - 1 + kw;
            if (iw < 0 || iw >= 128) continue;
            acc = fmaf(d[(b * 256 + ih) * 128 + iw], w[oc * 9 + kh * 3 + kw], acc);
        }
    }
    out[idx] = __float2bfloat16(acc);
}

// conv2 MFMA: in NHWC (64,128,64,64) bf16, w2t [128][576] bf16
//            -> out NHWC (64,64,32,128) bf16
// M-tile = 64 positions (2 oh x 32 ow), N = 128 oc, K = 9*64.
__global__ __launch_bounds__(256) void conv2_mfma(
    const __hip_bfloat16* __restrict__ in, const __hip_bfloat16* __restrict__ w2t,
    const float* __restrict__ bias, __hip_bfloat16* __restrict__ out)
{
    __shared__ short A_lds[64][32];
    __shared__ short B_lds[128][32];
    int tid = threadIdx.x;
    int oh0 = blockIdx.x * 2;
    int b   = blockIdx.y;
    int lane = tid & 63, wave = tid >> 6;
    int wr = wave >> 1, wc = wave & 1;
    floatx4 acc[2][4] = {};

    int ar = tid >> 2, aseg = tid & 3;      // A: row (=position), 16B segment
    int aohl = ar >> 5, aow = ar & 31;
    int boc = tid >> 2, bseg = tid & 3;     // B: oc row 0..63 (+64 second pass)

    const short* inp  = (const short*)in;
    const short* w2p  = (const short*)w2t;

    for (int s = 0; s < 9; ++s) {
        int kh = s / 3, kw = s % 3;
        int ih = 2 * (oh0 + aohl) - 1 + kh;
        int iw = 2 * aow - 1 + kw;
        bool inb = ((unsigned)ih < 128u) & ((unsigned)iw < 64u);
        const short* asrc = inp + (((b * 128 + ih) * 64 + iw) * 64 + aseg * 8);
#pragma unroll
        for (int half = 0; half < 2; ++half) {
            int koff = s * 64 + half * 32;
            short8 av = {0,0,0,0,0,0,0,0};
            if (inb) av = *(const short8*)(asrc + half * 32);
            short8 bv0 = *(const short8*)(w2p + boc * 576 + koff + bseg * 8);
            short8 bv1 = *(const short8*)(w2p + (boc + 64) * 576 + koff + bseg * 8);
            __syncthreads();
            *(short8*)&A_lds[ar][aseg * 8] = av;
            *(short8*)&B_lds[boc][bseg * 8] = bv0;
            *(short8*)&B_lds[boc + 64][bseg * 8] = bv1;
            __syncthreads();
            short8 a0 = *(const short8*)&A_lds[wr * 32 + (lane & 15)][(lane >> 4) * 8];
            short8 a1 = *(const short8*)&A_lds[wr * 32 + 16 + (lane & 15)][(lane >> 4) * 8];
#pragma unroll
            for (int ni = 0; ni < 4; ++ni) {
                short8 bv = *(const short8*)&B_lds[wc * 64 + ni * 16 + (lane & 15)][(lane >> 4) * 8];
                acc[0][ni] = __builtin_amdgcn_mfma_f32_16x16x32_bf16(a0, bv, acc[0][ni], 0, 0, 0);
                acc[1][ni] = __builtin_amdgcn_mfma_f32_16x16x32_bf16(a1, bv, acc[1][ni], 0, 0, 0);
            }
        }
    }
    // epilogue: C row = (lane>>4)*4+r, col = lane&15
    float bf[4];
#pragma unroll
    for (int ni = 0; ni < 4; ++ni) bf[ni] = bias[wc * 64 + ni * 16 + (lane & 15)];
#pragma unroll
    for (int mi = 0; mi < 2; ++mi)
#pragma unroll
        for (int r = 0; r < 4; ++r) {
            int m = wr * 32 + mi * 16 + (lane >> 4) * 4 + r;
            int ohl = m >> 5, ow = m & 31;
            __hip_bfloat16* op = out + (((long)(b * 64 + oh0 + ohl) * 32) + ow) * 128;
#pragma unroll
            for (int ni = 0; ni < 4; ++ni) {
                int oc = wc * 64 + ni * 16 + (lane & 15);
                op[oc] = __float2bfloat16(acc[mi][ni][r] + bf[ni]);
            }
        }
}

// conv3 MFMA: in NHWC (64,64,32,128) bf16, w3t [128][1152] bf16
//            -> dep (64*512, 128) fp32   (rows = oh*16+ow)
// M-tile = 64 positions (4 oh x 16 ow), K = 9*128.
__global__ __launch_bounds__(256) void conv3_mfma(
    const __hip_bfloat16* __restrict__ in, const __hip_bfloat16* __restrict__ w3t,
    const float* __restrict__ bias, float* __restrict__ dep)
{
    __shared__ short A_lds[64][32];
    __shared__ short B_lds[128][32];
    int tid = threadIdx.x;
    int oh0 = blockIdx.x * 4;
    int b   = blockIdx.y;
    int lane = tid & 63, wave = tid >> 6;
    int wr = wave >> 1, wc = wave & 1;
    floatx4 acc[2][4] = {};

    int ar = tid >> 2, aseg = tid & 3;
    int aohl = ar >> 4, aow = ar & 15;
    int boc = tid >> 2, bseg = tid & 3;

    const short* inp = (const short*)in;
    const short* w3p = (const short*)w3t;

    for (int s = 0; s < 9; ++s) {
        int kh = s / 3, kw = s % 3;
        int ih = 2 * (oh0 + aohl) - 1 + kh;
        int iw = 2 * aow - 1 + kw;
        bool inb = ((unsigned)ih < 64u) & ((unsigned)iw < 32u);
        const short* asrc = inp + (((b * 64 + ih) * 32 + iw) * 128 + aseg * 8);
#pragma unroll
        for (int q = 0; q < 4; ++q) {
            int koff = s * 128 + q * 32;
            short8 av = {0,0,0,0,0,0,0,0};
            if (inb) av = *(const short8*)(asrc + q * 32);
            short8 bv0 = *(const short8*)(w3p + boc * 1152 + koff + bseg * 8);
            short8 bv1 = *(const short8*)(w3p + (boc + 64) * 1152 + koff + bseg * 8);
            __syncthreads();
            *(short8*)&A_lds[ar][aseg * 8] = av;
            *(short8*)&B_lds[boc][bseg * 8] = bv0;
            *(short8*)&B_lds[boc + 64][bseg * 8] = bv1;
            __syncthreads();
            short8 a0 = *(const short8*)&A_lds[wr * 32 + (lane & 15)][(lane >> 4) * 8];
            short8 a1 = *(const short8*)&A_lds[wr * 32 + 16 + (lane & 15)][(lane >> 4) * 8];
#pragma unroll
            for (int ni = 0; ni < 4; ++ni) {
                short8 bv = *(const short8*)&B_lds[wc * 64 + ni * 16 + (lane & 15)][(lane >> 4) * 8];
                acc[0][ni] = __builtin_amdgcn_mfma_f32_16x16x32_bf16(a0, bv, acc[0][ni], 0, 0, 0);
                acc[1][ni] = __builtin_amdgcn_mfma_f32_16x16x32_bf16(a1, bv, acc[1][ni], 0, 0, 0);
            }
        }
    }
    float bf[4];
#pragma unroll
    for (int ni = 0; ni < 4; ++ni) bf[ni] = bias[wc * 64 + ni * 16 + (lane & 15)];
#pragma unroll
    for (int mi = 0; mi < 2; ++mi)
#pragma unroll
        for (int r = 0; r < 4; ++r) {
            int m = wr * 32 + mi * 16 + (lane >> 4) * 4 + r;
            float* op = dep + ((long)b * 512 + oh0 * 16 + m) * 128;
#pragma unroll
            for (int ni = 0; ni < 4; ++ni) {
                int oc = wc * 64 + ni * 16 + (lane & 15);
                op[oc] = acc[mi][ni][r] + bf[ni];
            }
        }
}

// c0[j] = g_depth @ W_merge[0:128] + b_merge
__global__ void c0_k(const float* __restrict__ g_depth, const float* __restrict__ Wm,
                     const float* __restrict__ bm, float* __restrict__ c0)
{
    int j = threadIdx.x;
    float acc = bm[j];
    for (int k = 0; k < 128; ++k) acc = fmaf(g_depth[k], Wm[k * 128 + j], acc);
    c0[j] = acc;
}

// sel postprocess: sigmoid + slice + softmax(attn)
__global__ __launch_bounds__(64) void sel_post_k(
    const float* __restrict__ raw, float* __restrict__ lx,
    float* __restrict__ ly, float* __restrict__ attn)
{
    int row = blockIdx.x;
    int t = threadIdx.x;
    __shared__ float a_s[24];
    __shared__ float red[2];
    const float* r = raw + row * 72;
    float lxv = 0.f, lyv = 0.f;
    if (t < 24) {
        lxv = 1.f / (1.f + expf(-r[2 * t]));
        lyv = 1.f / (1.f + expf(-r[2 * t + 1]));
        a_s[t] = 1.f / (1.f + expf(-r[48 + t]));
    }
    __syncthreads();
    if (t == 0) {
        float mx = a_s[0];
        for (int k = 1; k < 24; ++k) mx = fmaxf(mx, a_s[k]);
        float s = 0.f;
        for (int k = 0; k < 24; ++k) s += expf(a_s[k] - mx);
        red[0] = mx; red[1] = s;
    }
    __syncthreads();
    if (t < 24) {
        lx[row * 24 + t] = lxv;
        ly[row * 24 + t] = lyv;
        attn[row * 24 + t] = expf(a_s[t] - red[0]) / red[1];
    }
}

// bilinear gather + attn-weighted mean over 24 keypoints
__global__ __launch_bounds__(128) void r2d_k(
    const float* __restrict__ v, const float* __restrict__ lx,
    const float* __restrict__ ly, const float* __restrict__ attn,
    float* __restrict__ r2d)
{
    int n = blockIdx.x;
    int b = blockIdx.y;
    int c = threadIdx.x;
    int row = b * 128 + n;
    __shared__ float sx[24], sy[24], sa[24];
    if (c < 24) { sx[c] = lx[row * 24 + c]; sy[c] = ly[row * 24 + c]; sa[c] = attn[row * 24 + c]; }
    __syncthreads();
    const float* vb = v + (long)b * 512 * 128;
    float acc = 0.f;
    for (int k = 0; k < 24; ++k) {
        float lxv = sx[k], lyv = sy[k], a = sa[k];
        float x1 = floorf(lxv * 15.f), x2 = fminf(x1 + 1.f, 15.f);
        float y1 = floorf(lyv * 31.f), y2 = fminf(y1 + 1.f, 31.f);
        int xi1 = (int)x1, xi2 = (int)x2, yi1 = (int)y1, yi2 = (int)y2;
        float f0 = vb[(xi1 * 16 + yi2) * 128 + c];
        float f1 = vb[(xi2 * 16 + yi2) * 128 + c];
        float f2 = vb[(xi2 * 16 + yi1) * 128 + c];
        float f3 = vb[(xi1 * 16 + yi1) * 128 + c];
        float x = lxv * 16.f, y = lyv * 32.f;
        float w_ = x2 - x1, h_ = y2 - y1;
        float hwp = h_ * w_;
        bool deg = (h_ == 0.f) || (w_ == 0.f);
        float denom = (hwp == 0.f) ? 1.f : hwp;
        float coeff = deg ? 2.f : 1.f / denom;
        float xv0 = (w_ == 0.f) ? 1.f : (x2 - x);
        float xv1 = (w_ == 0.f) ? 1.f : (x - x1);
        float yv0 = (h_ == 0.f) ? 1.f : (y2 - y);
        float yv1 = (h_ == 0.f) ? 1.f : (y - y1);
        float interp = coeff * (xv0 * (f0 * yv0 + f1 * yv1) + xv1 * (f2 * yv0 + f3 * yv1));
        acc = fmaf(interp, a, acc);
    }
    r2d[(long)row * 128 + c] = acc * (1.f / 24.f);
}

// final_embedding[b,c] = mean over n of r2d
__global__ __launch_bounds__(128) void fe_k(const float* __restrict__ r2d,
                                            float* __restrict__ fe)
{
    int b = blockIdx.x;
    int c = threadIdx.x;
    float acc = 0.f;
    for (int nn = 0; nn < 128; ++nn) acc += r2d[((long)b * 128 + nn) * 128 + c];
    fe[b * 128 + c] = acc * (1.f / 128.f);
}

extern "C" void kernel_launch(void* const* d_in, const int* in_sizes, int n_in,
                              void* d_out, int out_size, void* d_ws, size_t ws_size,
                              hipStream_t stream)
{
    const float* features = (const float*)d_in[0];
    const float* d        = (const float*)d_in[1];
    const float* W_rg  = (const float*)d_in[2];
    const float* b_rg  = (const float*)d_in[3];
    const float* W_rl  = (const float*)d_in[4];
    const float* b_rl  = (const float*)d_in[5];
    const float* c1w   = (const float*)d_in[6];
    const float* c1b   = (const float*)d_in[7];
    const float* c2w   = (const float*)d_in[8];
    const float* c2b   = (const float*)d_in[9];
    const float* c3w   = (const float*)d_in[10];
    const float* c3b   = (const float*)d_in[11];
    const float* g_depth = (const float*)d_in[12];
    const float* W_merge = (const float*)d_in[13];
    const float* b_merge = (const float*)d_in[14];
    const float* W_q   = (const float*)d_in[15];
    const float* b_q   = (const float*)d_in[16];
    const float* W_v   = (const float*)d_in[17];
    const float* b_v   = (const float*)d_in[18];
    const float* W_sel = (const float*)d_in[19];
    const float* b_sel = (const float*)d_in[20];
    const float* W_cls = (const float*)d_in[21];
    float* out = (float*)d_out;

    char* ws = (char*)d_ws;
    // Overlaid layout (c1 region reused by dep/merged/v after conv2):
    __hip_bfloat16* c1 = (__hip_bfloat16*)(ws + 0);            // NHWC 67,108,864 B
    float* dep    = (float*)(ws + 0);                          // 16,777,216 (after c1 dead)
    float* merged = (float*)(ws + 16777216);                   // 16,777,216
    float* v      = (float*)(ws + 33554432);                   // 16,777,216
    __hip_bfloat16* c2 = (__hip_bfloat16*)(ws + 67108864);     // NHWC 33,554,432
    float* lfeat  = (float*)(ws + 100663296);                  // 4,194,304 (written AFTER convs)
    float* q      = (float*)(ws + 104857600);                  // 4,194,304
    float* selraw = (float*)(ws + 109051904);                  // 2,359,296
    float* lxb    = (float*)(ws + 111411200);                  // 786,432
    float* lyb    = (float*)(ws + 112197632);                  // 786,432
    float* attnb  = (float*)(ws + 112984064);                  // 786,432
    float* gfeat  = (float*)(ws + 113770496);                  // 32,768
    float* gq     = (float*)(ws + 113803264);                  // 32,768
    float* c0b    = (float*)(ws + 113836032);                  // 512
    float* r2d    = (float*)(ws + 113836544);                  // 4,194,304
    // transformed weights overlaid on lfeat region (dead until feature path,
    // which launches after conv3 — safe by stream ordering):
    __hip_bfloat16* w2t = (__hip_bfloat16*)(ws + 100663296);          // 147,456 B
    __hip_bfloat16* w3t = (__hip_bfloat16*)(ws + 100663296 + 147456); // 294,912 B

    float* fe = out + 64 * 751;

    // ---- weight transforms ----
    wt2_k<<<288, 256, 0, stream>>>(c2w, w2t);
    wt3_k<<<576, 256, 0, stream>>>(c3w, w3t);

    // ---- conv path (MFMA) ----
    conv1_k<<<131072, 256, 0, stream>>>(d, c1w, c1b, c1);
    conv2_mfma<<<dim3(32, 64), 256, 0, stream>>>(c1, w2t, c2b, c2);
    conv3_mfma<<<dim3(8, 64), 256, 0, stream>>>(c2, w3t, c3b, dep);
    c0_k<<<1, 128, 0, stream>>>(g_depth, W_merge, b_merge, c0b);
    // merged = dep @ W_merge[128:] + c0
    gemm_f32<<<dim3(2, 512), 256, 0, stream>>>(dep, W_merge + 128 * 128, c0b, merged,
                                               32768, 128, 128, 128, 128, 128, 0, 1);
    // v = merged @ W_v + b_v
    gemm_f32<<<dim3(2, 512), 256, 0, stream>>>(merged, W_v, b_v, v,
                                               32768, 128, 128, 128, 128, 128, 0, 1);

    // ---- feature path ----
    gemm_f32<<<dim3(2, 1), 256, 0, stream>>>(features, W_rg, b_rg, gfeat,
                                             64, 128, 768, 768, 128, 128, 2, 1);
    gemm_f32<<<dim3(2, 1), 256, 0, stream>>>(gfeat, W_q, b_q, gq,
                                             64, 128, 128, 128, 128, 128, 0, 1);
    gemm_f32<<<dim3(2, 128), 256, 0, stream>>>(features, W_rl, b_rl, lfeat,
                                               8192, 128, 768, 768, 128, 128, 1, 1);
    gemm_f32<<<dim3(2, 128), 256, 0, stream>>>(lfeat, W_q + 128 * 128, gq, q,
                                               8192, 128, 128, 128, 128, 128, 0, 2);
    gemm_f32<<<dim3(2, 128), 256, 0, stream>>>(q, W_sel, b_sel, selraw,
                                               8192, 72, 128, 128, 72, 72, 0, 1);
    sel_post_k<<<8192, 64, 0, stream>>>(selraw, lxb, lyb, attnb);

    // ---- fusion tail ----
    r2d_k<<<dim3(128, 64), 128, 0, stream>>>(v, lxb, lyb, attnb, r2d);
    fe_k<<<64, 128, 0, stream>>>(r2d, fe);
    gemm_f32<<<dim3(12, 1), 256, 0, stream>>>(fe, W_cls, nullptr, out,
                                              64, 751, 128, 128, 751, 751, 0, 0);
}

// Round 5
// 315.305 us; speedup vs baseline: 9.3265x; 1.9813x over previous
//
#include <hip/hip_runtime.h>
#include <hip/hip_bf16.h>

// ---------------------------------------------------------------------------
// FourDNet forward. Convs = bf16 MFMA implicit GEMM (NHWC), GEMM chain folded:
//   v      = dep @ (W_merge_bot @ W_v) + (c0 @ W_v + b_v)
//   selraw = features[:,1:] @ (W_rl @ W_qs_bot) + rowbias[b]
//   where W_qs = W_q @ W_sel, rowbias = gfeat @ W_qs_top + vbias
// B=64, N=128, RED=128, MK=24, HD=32, WD=16.
// d_out layout: [cls_score 64*751][final_embedding 64*128], fp32.
//
// WS layout rule learned round 4: prep/folded buffers MUST live outside
// ws[0..64MB] (c1 NHWC region, rewritten by conv1 after prep kernels run).
// They now live at ws+101.1MB (dead gap between w3t and selraw).
// ---------------------------------------------------------------------------

typedef __attribute__((ext_vector_type(8))) short short8;
typedef __attribute__((ext_vector_type(4))) float floatx4;

#define TS 64
#define KS 16

// Generic tiled GEMM: C[M,N] = A[M,K] @ B[K,N] (+bias)
// a_mode: 0 identity rows, 1 features-local rows (m + (m>>7) + 1)
// bias_mode: 0 none, 1 per-col bias[N], 2 per-row-block bias[(m>>7)*N + n]
__global__ __launch_bounds__(256) void gemm_f32(
    const float* __restrict__ A, const float* __restrict__ B,
    const float* __restrict__ bias, float* __restrict__ C,
    int M, int N, int K, int lda, int ldb, int ldc,
    int a_mode, int bias_mode)
{
    __shared__ float As[KS][TS + 1];
    __shared__ float Bs[KS][TS + 4];
    int tid = threadIdx.x;
    int tx = tid & 15, ty = tid >> 4;
    int n0 = blockIdx.x * TS;
    int m0 = blockIdx.y * TS;
    float acc[4][4] = {};

    int a_k = tid & 15;
    int a_m = tid >> 4;
    int b_n = tid & 63;
    int b_k = tid >> 6;

    for (int k0 = 0; k0 < K; k0 += KS) {
#pragma unroll
        for (int p = 0; p < 4; ++p) {
            int m = a_m + p * 16;
            int gm = m0 + m;
            int pr = (a_mode == 1) ? (gm + (gm >> 7) + 1) : gm;
            As[a_k][m] = A[(long)pr * lda + k0 + a_k];
        }
#pragma unroll
        for (int p = 0; p < 4; ++p) {
            int k = b_k + p * 4;
            int gn = n0 + b_n;
            Bs[k][b_n] = (gn < N) ? B[(long)(k0 + k) * ldb + gn] : 0.f;
        }
        __syncthreads();
#pragma unroll
        for (int k = 0; k < KS; ++k) {
            float a[4], b[4];
#pragma unroll
            for (int i = 0; i < 4; ++i) a[i] = As[k][ty * 4 + i];
#pragma unroll
            for (int j = 0; j < 4; ++j) b[j] = Bs[k][tx * 4 + j];
#pragma unroll
            for (int i = 0; i < 4; ++i)
#pragma unroll
                for (int j = 0; j < 4; ++j)
                    acc[i][j] = fmaf(a[i], b[j], acc[i][j]);
        }
        __syncthreads();
    }
#pragma unroll
    for (int i = 0; i < 4; ++i) {
        int m = m0 + ty * 4 + i;
#pragma unroll
        for (int j = 0; j < 4; ++j) {
            int n = n0 + tx * 4 + j;
            if (n < N) {
                float v = acc[i][j];
                if (bias_mode == 1) v += bias[n];
                else if (bias_mode == 2) v += bias[(m >> 7) * N + n];
                C[(long)m * ldc + n] = v;
            }
        }
    }
}

// ---- prep1: W_qs [256][72], W_mv [128][128], c0 [128], gfeat [64][128] ----
__global__ __launch_bounds__(256) void prep1_k(
    const float* __restrict__ W_q, const float* __restrict__ W_sel,
    const float* __restrict__ W_merge, const float* __restrict__ W_v,
    const float* __restrict__ g_depth, const float* __restrict__ b_merge,
    const float* __restrict__ features, const float* __restrict__ W_rg,
    const float* __restrict__ b_rg,
    float* __restrict__ W_qs, float* __restrict__ W_mv,
    float* __restrict__ c0, float* __restrict__ gfeat)
{
    int bid = blockIdx.x, t = threadIdx.x;
    if (bid < 72) {                       // W_qs col j: rows i=t (256)
        int j = bid;
        float acc = 0.f;
        for (int k = 0; k < 128; ++k)
            acc = fmaf(W_q[t * 128 + k], W_sel[k * 72 + j], acc);
        W_qs[t * 72 + j] = acc;
    } else if (bid < 200) {               // W_mv col j: rows k=t (128)
        int j = bid - 72;
        if (t < 128) {
            float acc = 0.f;
            for (int k = 0; k < 128; ++k)
                acc = fmaf(W_merge[(128 + t) * 128 + k], W_v[k * 128 + j], acc);
            W_mv[t * 128 + j] = acc;
        }
    } else if (bid == 200) {              // c0
        if (t < 128) {
            float acc = b_merge[t];
            for (int k = 0; k < 128; ++k)
                acc = fmaf(g_depth[k], W_merge[k * 128 + t], acc);
            c0[t] = acc;
        }
    } else {                              // gfeat col j: rows b=t (64)
        int j = bid - 201;
        if (t < 64) {
            float acc = b_rg[j];
            const float* fr = features + (long)t * 129 * 768;
            for (int k = 0; k < 768; ++k)
                acc = fmaf(fr[k], W_rg[k * 128 + j], acc);
            gfeat[t * 128 + j] = acc;
        }
    }
}

// ---- prep2: W_big [768][72], rowbias [64][72], c0v [128] ----
__global__ __launch_bounds__(256) void prep2_k(
    const float* __restrict__ W_rl, const float* __restrict__ W_qs,
    const float* __restrict__ W_sel, const float* __restrict__ b_rl,
    const float* __restrict__ b_q, const float* __restrict__ b_sel,
    const float* __restrict__ gfeat, const float* __restrict__ c0,
    const float* __restrict__ W_v, const float* __restrict__ b_v,
    float* __restrict__ W_big, float* __restrict__ rowbias,
    float* __restrict__ c0v)
{
    int bid = blockIdx.x, t = threadIdx.x;
    if (bid < 216) {                      // W_big: col j = bid/3, rows chunk
        int j = bid / 3;
        int i = (bid % 3) * 256 + t;
        float acc = 0.f;
        for (int k = 0; k < 128; ++k)
            acc = fmaf(W_rl[i * 128 + k], W_qs[(128 + k) * 72 + j], acc);
        W_big[i * 72 + j] = acc;
    } else if (bid < 288) {               // rowbias col j: rows b=t (64)
        int j = bid - 216;
        if (t < 64) {
            float vb = b_sel[j];
            for (int k = 0; k < 128; ++k) {
                vb = fmaf(b_rl[k], W_qs[(128 + k) * 72 + j], vb);
                vb = fmaf(b_q[k], W_sel[k * 72 + j], vb);
            }
            float acc = vb;
            for (int k = 0; k < 128; ++k)
                acc = fmaf(gfeat[t * 128 + k], W_qs[k * 72 + j], acc);
            rowbias[t * 72 + j] = acc;
        }
    } else {                              // c0v
        if (t < 128) {
            float acc = b_v[t];
            for (int k = 0; k < 128; ++k)
                acc = fmaf(c0[k], W_v[k * 128 + t], acc);
            c0v[t] = acc;
        }
    }
}

// weight transform: OIHW fp32 -> [oc][(kh*3+kw)*IC + ic] bf16
__global__ __launch_bounds__(256) void wt2_k(const float* __restrict__ w,
                                             __hip_bfloat16* __restrict__ wt)
{
    int idx = blockIdx.x * 256 + threadIdx.x;
    if (idx >= 128 * 576) return;
    int oc = idx / 576, k = idx % 576;
    int s = k >> 6, ic = k & 63;
    wt[idx] = __float2bfloat16(w[oc * 576 + ic * 9 + s]);
}
__global__ __launch_bounds__(256) void wt3_k(const float* __restrict__ w,
                                             __hip_bfloat16* __restrict__ wt)
{
    int idx = blockIdx.x * 256 + threadIdx.x;
    if (idx >= 128 * 1152) return;
    int oc = idx / 1152, k = idx % 1152;
    int s = k >> 7, ic = k & 127;
    wt[idx] = __float2bfloat16(w[oc * 1152 + ic * 9 + s]);
}

// conv1: d (64,1,256,128) f32 -> out NHWC (64,128,64,64) bf16. stride2 pad1.
// Block = (b, oh, ow-half of 32). 256 thr = 32 pos x 8 oc-groups.
__global__ __launch_bounds__(256) void conv1_k(
    const float* __restrict__ d, const float* __restrict__ w,
    const float* __restrict__ bias, __hip_bfloat16* __restrict__ out)
{
    __shared__ float in_s[3][66];
    __shared__ float ws_[576];
    __shared__ float bs_[64];
    int tid = threadIdx.x;
    int owhalf = blockIdx.x & 1;
    int oh = (blockIdx.x >> 1) & 127;
    int b  = blockIdx.x >> 8;
    int owbase = owhalf * 32;

    for (int l = tid; l < 576; l += 256) ws_[l] = w[l];
    if (tid < 64) bs_[tid] = bias[tid];
    for (int l = tid; l < 3 * 66; l += 256) {
        int r = l / 66, c = l % 66;
        int ih = 2 * oh - 1 + r;
        int iw = 2 * owbase - 1 + c;
        float v = 0.f;
        if ((unsigned)ih < 256u && (unsigned)iw < 128u)
            v = d[(b * 256 + ih) * 128 + iw];
        in_s[r][c] = v;
    }
    __syncthreads();

    int owl = tid >> 3, ocg = tid & 7;
    float in9[9];
#pragma unroll
    for (int r = 0; r < 3; ++r)
#pragma unroll
        for (int c = 0; c < 3; ++c)
            in9[r * 3 + c] = in_s[r][2 * owl + c];

    short8 res;
#pragma unroll
    for (int j = 0; j < 8; ++j) {
        int oc = ocg * 8 + j;
        float a = bs_[oc];
#pragma unroll
        for (int s = 0; s < 9; ++s) a = fmaf(in9[s], ws_[oc * 9 + s], a);
        union { __hip_bfloat16 h; short s; } u;
        u.h = __float2bfloat16(a);
        res[j] = u.s;
    }
    long pos = ((long)(b * 128 + oh) * 64 + owbase + owl);
    *(short8*)((short*)out + pos * 64 + ocg * 8) = res;
}

// conv2 MFMA: in NHWC (64,128,64,64) bf16, w2t [128][576] bf16
//            -> out NHWC (64,64,32,128) bf16
__global__ __launch_bounds__(256) void conv2_mfma(
    const __hip_bfloat16* __restrict__ in, const __hip_bfloat16* __restrict__ w2t,
    const float* __restrict__ bias, __hip_bfloat16* __restrict__ out)
{
    __shared__ short A_lds[64][32];
    __shared__ short B_lds[128][32];
    int tid = threadIdx.x;
    int oh0 = blockIdx.x * 2;
    int b   = blockIdx.y;
    int lane = tid & 63, wave = tid >> 6;
    int wr = wave >> 1, wc = wave & 1;
    floatx4 acc[2][4] = {};

    int ar = tid >> 2, aseg = tid & 3;
    int aohl = ar >> 5, aow = ar & 31;
    int boc = tid >> 2, bseg = tid & 3;

    const short* inp  = (const short*)in;
    const short* w2p  = (const short*)w2t;

    for (int s = 0; s < 9; ++s) {
        int kh = s / 3, kw = s % 3;
        int ih = 2 * (oh0 + aohl) - 1 + kh;
        int iw = 2 * aow - 1 + kw;
        bool inb = ((unsigned)ih < 128u) & ((unsigned)iw < 64u);
        const short* asrc = inp + (((b * 128 + ih) * 64 + iw) * 64 + aseg * 8);
#pragma unroll
        for (int half = 0; half < 2; ++half) {
            int koff = s * 64 + half * 32;
            short8 av = {0,0,0,0,0,0,0,0};
            if (inb) av = *(const short8*)(asrc + half * 32);
            short8 bv0 = *(const short8*)(w2p + boc * 576 + koff + bseg * 8);
            short8 bv1 = *(const short8*)(w2p + (boc + 64) * 576 + koff + bseg * 8);
            __syncthreads();
            *(short8*)&A_lds[ar][aseg * 8] = av;
            *(short8*)&B_lds[boc][bseg * 8] = bv0;
            *(short8*)&B_lds[boc + 64][bseg * 8] = bv1;
            __syncthreads();
            short8 a0 = *(const short8*)&A_lds[wr * 32 + (lane & 15)][(lane >> 4) * 8];
            short8 a1 = *(const short8*)&A_lds[wr * 32 + 16 + (lane & 15)][(lane >> 4) * 8];
#pragma unroll
            for (int ni = 0; ni < 4; ++ni) {
                short8 bv = *(const short8*)&B_lds[wc * 64 + ni * 16 + (lane & 15)][(lane >> 4) * 8];
                acc[0][ni] = __builtin_amdgcn_mfma_f32_16x16x32_bf16(a0, bv, acc[0][ni], 0, 0, 0);
                acc[1][ni] = __builtin_amdgcn_mfma_f32_16x16x32_bf16(a1, bv, acc[1][ni], 0, 0, 0);
            }
        }
    }
    float bf[4];
#pragma unroll
    for (int ni = 0; ni < 4; ++ni) bf[ni] = bias[wc * 64 + ni * 16 + (lane & 15)];
#pragma unroll
    for (int mi = 0; mi < 2; ++mi)
#pragma unroll
        for (int r = 0; r < 4; ++r) {
            int m = wr * 32 + mi * 16 + (lane >> 4) * 4 + r;
            int ohl = m >> 5, ow = m & 31;
            __hip_bfloat16* op = out + (((long)(b * 64 + oh0 + ohl) * 32) + ow) * 128;
#pragma unroll
            for (int ni = 0; ni < 4; ++ni) {
                int oc = wc * 64 + ni * 16 + (lane & 15);
                op[oc] = __float2bfloat16(acc[mi][ni][r] + bf[ni]);
            }
        }
}

// conv3 MFMA: in NHWC (64,64,32,128) bf16, w3t [128][1152] bf16
//            -> dep (64*512, 128) fp32
__global__ __launch_bounds__(256) void conv3_mfma(
    const __hip_bfloat16* __restrict__ in, const __hip_bfloat16* __restrict__ w3t,
    const float* __restrict__ bias, float* __restrict__ dep)
{
    __shared__ short A_lds[64][32];
    __shared__ short B_lds[128][32];
    int tid = threadIdx.x;
    int oh0 = blockIdx.x * 4;
    int b   = blockIdx.y;
    int lane = tid & 63, wave = tid >> 6;
    int wr = wave >> 1, wc = wave & 1;
    floatx4 acc[2][4] = {};

    int ar = tid >> 2, aseg = tid & 3;
    int aohl = ar >> 4, aow = ar & 15;
    int boc = tid >> 2, bseg = tid & 3;

    const short* inp = (const short*)in;
    const short* w3p = (const short*)w3t;

    for (int s = 0; s < 9; ++s) {
        int kh = s / 3, kw = s % 3;
        int ih = 2 * (oh0 + aohl) - 1 + kh;
        int iw = 2 * aow - 1 + kw;
        bool inb = ((unsigned)ih < 64u) & ((unsigned)iw < 32u);
        const short* asrc = inp + (((b * 64 + ih) * 32 + iw) * 128 + aseg * 8);
#pragma unroll
        for (int q = 0; q < 4; ++q) {
            int koff = s * 128 + q * 32;
            short8 av = {0,0,0,0,0,0,0,0};
            if (inb) av = *(const short8*)(asrc + q * 32);
            short8 bv0 = *(const short8*)(w3p + boc * 1152 + koff + bseg * 8);
            short8 bv1 = *(const short8*)(w3p + (boc + 64) * 1152 + koff + bseg * 8);
            __syncthreads();
            *(short8*)&A_lds[ar][aseg * 8] = av;
            *(short8*)&B_lds[boc][bseg * 8] = bv0;
            *(short8*)&B_lds[boc + 64][bseg * 8] = bv1;
            __syncthreads();
            short8 a0 = *(const short8*)&A_lds[wr * 32 + (lane & 15)][(lane >> 4) * 8];
            short8 a1 = *(const short8*)&A_lds[wr * 32 + 16 + (lane & 15)][(lane >> 4) * 8];
#pragma unroll
            for (int ni = 0; ni < 4; ++ni) {
                short8 bv = *(const short8*)&B_lds[wc * 64 + ni * 16 + (lane & 15)][(lane >> 4) * 8];
                acc[0][ni] = __builtin_amdgcn_mfma_f32_16x16x32_bf16(a0, bv, acc[0][ni], 0, 0, 0);
                acc[1][ni] = __builtin_amdgcn_mfma_f32_16x16x32_bf16(a1, bv, acc[1][ni], 0, 0, 0);
            }
        }
    }
    float bf[4];
#pragma unroll
    for (int ni = 0; ni < 4; ++ni) bf[ni] = bias[wc * 64 + ni * 16 + (lane & 15)];
#pragma unroll
    for (int mi = 0; mi < 2; ++mi)
#pragma unroll
        for (int r = 0; r < 4; ++r) {
            int m = wr * 32 + mi * 16 + (lane >> 4) * 4 + r;
            float* op = dep + ((long)b * 512 + oh0 * 16 + m) * 128;
#pragma unroll
            for (int ni = 0; ni < 4; ++ni) {
                int oc = wc * 64 + ni * 16 + (lane & 15);
                op[oc] = acc[mi][ni][r] + bf[ni];
            }
        }
}

// sel postprocess: sigmoid + slice + softmax(attn)
__global__ __launch_bounds__(64) void sel_post_k(
    const float* __restrict__ raw, float* __restrict__ lx,
    float* __restrict__ ly, float* __restrict__ attn)
{
    int row = blockIdx.x;
    int t = threadIdx.x;
    __shared__ float a_s[24];
    __shared__ float red[2];
    const float* r = raw + row * 72;
    float lxv = 0.f, lyv = 0.f;
    if (t < 24) {
        lxv = 1.f / (1.f + expf(-r[2 * t]));
        lyv = 1.f / (1.f + expf(-r[2 * t + 1]));
        a_s[t] = 1.f / (1.f + expf(-r[48 + t]));
    }
    __syncthreads();
    if (t == 0) {
        float mx = a_s[0];
        for (int k = 1; k < 24; ++k) mx = fmaxf(mx, a_s[k]);
        float s = 0.f;
        for (int k = 0; k < 24; ++k) s += expf(a_s[k] - mx);
        red[0] = mx; red[1] = s;
    }
    __syncthreads();
    if (t < 24) {
        lx[row * 24 + t] = lxv;
        ly[row * 24 + t] = lyv;
        attn[row * 24 + t] = expf(a_s[t] - red[0]) / red[1];
    }
}

// bilinear gather + attn-weighted mean over 24 keypoints
__global__ __launch_bounds__(128) void r2d_k(
    const float* __restrict__ v, const float* __restrict__ lx,
    const float* __restrict__ ly, const float* __restrict__ attn,
    float* __restrict__ r2d)
{
    int n = blockIdx.x;
    int b = blockIdx.y;
    int c = threadIdx.x;
    int row = b * 128 + n;
    __shared__ float sx[24], sy[24], sa[24];
    if (c < 24) { sx[c] = lx[row * 24 + c]; sy[c] = ly[row * 24 + c]; sa[c] = attn[row * 24 + c]; }
    __syncthreads();
    const float* vb = v + (long)b * 512 * 128;
    float acc = 0.f;
    for (int k = 0; k < 24; ++k) {
        float lxv = sx[k], lyv = sy[k], a = sa[k];
        float x1 = floorf(lxv * 15.f), x2 = fminf(x1 + 1.f, 15.f);
        float y1 = floorf(lyv * 31.f), y2 = fminf(y1 + 1.f, 31.f);
        int xi1 = (int)x1, xi2 = (int)x2, yi1 = (int)y1, yi2 = (int)y2;
        float f0 = vb[(xi1 * 16 + yi2) * 128 + c];
        float f1 = vb[(xi2 * 16 + yi2) * 128 + c];
        float f2 = vb[(xi2 * 16 + yi1) * 128 + c];
        float f3 = vb[(xi1 * 16 + yi1) * 128 + c];
        float x = lxv * 16.f, y = lyv * 32.f;
        float w_ = x2 - x1, h_ = y2 - y1;
        float hwp = h_ * w_;
        bool deg = (h_ == 0.f) || (w_ == 0.f);
        float denom = (hwp == 0.f) ? 1.f : hwp;
        float coeff = deg ? 2.f : 1.f / denom;
        float xv0 = (w_ == 0.f) ? 1.f : (x2 - x);
        float xv1 = (w_ == 0.f) ? 1.f : (x - x1);
        float yv0 = (h_ == 0.f) ? 1.f : (y2 - y);
        float yv1 = (h_ == 0.f) ? 1.f : (y - y1);
        float interp = coeff * (xv0 * (f0 * yv0 + f1 * yv1) + xv1 * (f2 * yv0 + f3 * yv1));
        acc = fmaf(interp, a, acc);
    }
    r2d[(long)row * 128 + c] = acc * (1.f / 24.f);
}

// final_embedding[b,c] = mean over n of r2d
__global__ __launch_bounds__(128) void fe_k(const float* __restrict__ r2d,
                                            float* __restrict__ fe)
{
    int b = blockIdx.x;
    int c = threadIdx.x;
    float acc = 0.f;
    for (int nn = 0; nn < 128; ++nn) acc += r2d[((long)b * 128 + nn) * 128 + c];
    fe[b * 128 + c] = acc * (1.f / 128.f);
}

extern "C" void kernel_launch(void* const* d_in, const int* in_sizes, int n_in,
                              void* d_out, int out_size, void* d_ws, size_t ws_size,
                              hipStream_t stream)
{
    const float* features = (const float*)d_in[0];
    const float* d        = (const float*)d_in[1];
    const float* W_rg  = (const float*)d_in[2];
    const float* b_rg  = (const float*)d_in[3];
    const float* W_rl  = (const float*)d_in[4];
    const float* b_rl  = (const float*)d_in[5];
    const float* c1w   = (const float*)d_in[6];
    const float* c1b   = (const float*)d_in[7];
    const float* c2w   = (const float*)d_in[8];
    const float* c2b   = (const float*)d_in[9];
    const float* c3w   = (const float*)d_in[10];
    const float* c3b   = (const float*)d_in[11];
    const float* g_depth = (const float*)d_in[12];
    const float* W_merge = (const float*)d_in[13];
    const float* b_merge = (const float*)d_in[14];
    const float* W_q   = (const float*)d_in[15];
    const float* b_q   = (const float*)d_in[16];
    const float* W_v   = (const float*)d_in[17];
    const float* b_v   = (const float*)d_in[18];
    const float* W_sel = (const float*)d_in[19];
    const float* b_sel = (const float*)d_in[20];
    const float* W_cls = (const float*)d_in[21];
    float* out = (float*)d_out;

    char* ws = (char*)d_ws;
    __hip_bfloat16* c1 = (__hip_bfloat16*)(ws + 0);            // NHWC, ws[0 .. 67,108,864)
    float* dep    = (float*)(ws + 0);                          // 16,777,216 (c1 dead after conv2)
    float* v      = (float*)(ws + 33554432);                   // 16,777,216 (inside old c1, written post-conv2)
    __hip_bfloat16* c2 = (__hip_bfloat16*)(ws + 67108864);     // NHWC 33,554,432
    __hip_bfloat16* w2t = (__hip_bfloat16*)(ws + 100663296);          // 147,456
    __hip_bfloat16* w3t = (__hip_bfloat16*)(ws + 100810752);          // 294,912
    // folded-weight buffers: dead gap, untouched by convs (ends < selraw@109MB)
    float* W_qs    = (float*)(ws + 101105664);                 // 73,728
    float* W_mv    = (float*)(ws + 101179392);                 // 65,536
    float* W_big   = (float*)(ws + 101244928);                 // 221,184
    float* rowbias = (float*)(ws + 101466112);                 // 18,432
    float* c0b     = (float*)(ws + 101484544);                 // 512
    float* c0v     = (float*)(ws + 101485056);                 // 512
    float* gfeat   = (float*)(ws + 101485568);                 // 32,768 (ends 101,518,336)
    float* selraw = (float*)(ws + 109051904);                  // 2,359,296
    float* lxb    = (float*)(ws + 111411200);                  // 786,432
    float* lyb    = (float*)(ws + 112197632);                  // 786,432
    float* attnb  = (float*)(ws + 112984064);                  // 786,432
    float* r2d    = (float*)(ws + 113836544);                  // 4,194,304

    float* fe = out + 64 * 751;

    // ---- prep (folded weights) ----
    prep1_k<<<329, 256, 0, stream>>>(W_q, W_sel, W_merge, W_v, g_depth, b_merge,
                                     features, W_rg, b_rg, W_qs, W_mv, c0b, gfeat);
    prep2_k<<<289, 256, 0, stream>>>(W_rl, W_qs, W_sel, b_rl, b_q, b_sel,
                                     gfeat, c0b, W_v, b_v, W_big, rowbias, c0v);
    wt2_k<<<288, 256, 0, stream>>>(c2w, w2t);
    wt3_k<<<576, 256, 0, stream>>>(c3w, w3t);

    // ---- conv path (MFMA) ----
    conv1_k<<<16384, 256, 0, stream>>>(d, c1w, c1b, c1);
    conv2_mfma<<<dim3(32, 64), 256, 0, stream>>>(c1, w2t, c2b, c2);
    conv3_mfma<<<dim3(8, 64), 256, 0, stream>>>(c2, w3t, c3b, dep);

    // v = dep @ W_mv + c0v
    gemm_f32<<<dim3(2, 512), 256, 0, stream>>>(dep, W_mv, c0v, v,
                                               32768, 128, 128, 128, 128, 128, 0, 1);
    // selraw = features[:,1:] @ W_big + rowbias[b]
    gemm_f32<<<dim3(2, 128), 256, 0, stream>>>(features, W_big, rowbias, selraw,
                                               8192, 72, 768, 768, 72, 72, 1, 2);
    sel_post_k<<<8192, 64, 0, stream>>>(selraw, lxb, lyb, attnb);

    // ---- fusion tail ----
    r2d_k<<<dim3(128, 64), 128, 0, stream>>>(v, lxb, lyb, attnb, r2d);
    fe_k<<<64, 128, 0, stream>>>(r2d, fe);
    gemm_f32<<<dim3(12, 1), 256, 0, stream>>>(fe, W_cls, nullptr, out,
                                              64, 751, 128, 128, 751, 751, 0, 0);
}

// Round 6
// 282.965 us; speedup vs baseline: 10.3925x; 1.1143x over previous
//
#include <hip/hip_runtime.h>
#include <hip/hip_bf16.h>

// ---------------------------------------------------------------------------
// FourDNet forward. Convs = bf16 MFMA implicit GEMM (NHWC). Folded chain:
//   v      = dep @ (W_merge_bot @ W_v) + c0v          [MFMA hi/lo split]
//   sel    = sigmoid(F[:,1:] @ W_big + rowbias[b])    [fp32, fused softmax]
// WS rule (round 4): prep/folded buffers live outside ws[0..64MB] (c1 region).
// selraw GEMM redesign (round 6): 32 rows x 9-out threads, K-chunk 96,
//   fused sigmoid+softmax; fp32 mandatory (lx/ly feed discontinuous floor()).
// ---------------------------------------------------------------------------

typedef __attribute__((ext_vector_type(8))) short short8;
typedef __attribute__((ext_vector_type(4))) short shortx4;
typedef __attribute__((ext_vector_type(4))) float floatx4;

// ---- prep1: W_qs [256][72], W_mv [128][128], c0 [128], gfeat [64][128] ----
__global__ __launch_bounds__(256) void prep1_k(
    const float* __restrict__ W_q, const float* __restrict__ W_sel,
    const float* __restrict__ W_merge, const float* __restrict__ W_v,
    const float* __restrict__ g_depth, const float* __restrict__ b_merge,
    const float* __restrict__ features, const float* __restrict__ W_rg,
    const float* __restrict__ b_rg,
    float* __restrict__ W_qs, float* __restrict__ W_mv,
    float* __restrict__ c0, float* __restrict__ gfeat)
{
    int bid = blockIdx.x, t = threadIdx.x;
    if (bid < 72) {
        int j = bid;
        float acc = 0.f;
        for (int k = 0; k < 128; ++k)
            acc = fmaf(W_q[t * 128 + k], W_sel[k * 72 + j], acc);
        W_qs[t * 72 + j] = acc;
    } else if (bid < 200) {
        int j = bid - 72;
        if (t < 128) {
            float acc = 0.f;
            for (int k = 0; k < 128; ++k)
                acc = fmaf(W_merge[(128 + t) * 128 + k], W_v[k * 128 + j], acc);
            W_mv[t * 128 + j] = acc;
        }
    } else if (bid == 200) {
        if (t < 128) {
            float acc = b_merge[t];
            for (int k = 0; k < 128; ++k)
                acc = fmaf(g_depth[k], W_merge[k * 128 + t], acc);
            c0[t] = acc;
        }
    } else {
        int j = bid - 201;
        if (t < 64) {
            float acc = b_rg[j];
            const float* fr = features + (long)t * 129 * 768;
            for (int k = 0; k < 768; ++k)
                acc = fmaf(fr[k], W_rg[k * 128 + j], acc);
            gfeat[t * 128 + j] = acc;
        }
    }
}

// ---- prep2: W_big [768][72], rowbias [64][72], c0v [128] ----
__global__ __launch_bounds__(256) void prep2_k(
    const float* __restrict__ W_rl, const float* __restrict__ W_qs,
    const float* __restrict__ W_sel, const float* __restrict__ b_rl,
    const float* __restrict__ b_q, const float* __restrict__ b_sel,
    const float* __restrict__ gfeat, const float* __restrict__ c0,
    const float* __restrict__ W_v, const float* __restrict__ b_v,
    float* __restrict__ W_big, float* __restrict__ rowbias,
    float* __restrict__ c0v)
{
    int bid = blockIdx.x, t = threadIdx.x;
    if (bid < 216) {
        int j = bid / 3;
        int i = (bid % 3) * 256 + t;
        float acc = 0.f;
        for (int k = 0; k < 128; ++k)
            acc = fmaf(W_rl[i * 128 + k], W_qs[(128 + k) * 72 + j], acc);
        W_big[i * 72 + j] = acc;
    } else if (bid < 288) {
        int j = bid - 216;
        if (t < 64) {
            float vb = b_sel[j];
            for (int k = 0; k < 128; ++k) {
                vb = fmaf(b_rl[k], W_qs[(128 + k) * 72 + j], vb);
                vb = fmaf(b_q[k], W_sel[k * 72 + j], vb);
            }
            float acc = vb;
            for (int k = 0; k < 128; ++k)
                acc = fmaf(gfeat[t * 128 + k], W_qs[k * 72 + j], acc);
            rowbias[t * 72 + j] = acc;
        }
    } else {
        if (t < 128) {
            float acc = b_v[t];
            for (int k = 0; k < 128; ++k)
                acc = fmaf(c0[k], W_v[k * 128 + t], acc);
            c0v[t] = acc;
        }
    }
}

// ---- prep3: W_mv -> B-transposed bf16 hi/lo [n][k] ----
__global__ __launch_bounds__(256) void prep3_k(
    const float* __restrict__ W_mv,
    __hip_bfloat16* __restrict__ Bh, __hip_bfloat16* __restrict__ Bl)
{
    int idx = blockIdx.x * 256 + threadIdx.x;   // 16384
    int n = idx >> 7, k = idx & 127;
    float w = W_mv[k * 128 + n];
    __hip_bfloat16 h = __float2bfloat16(w);
    Bh[idx] = h;
    Bl[idx] = __float2bfloat16(w - __bfloat162float(h));
}

// weight transform: OIHW fp32 -> [oc][(kh*3+kw)*IC + ic] bf16
__global__ __launch_bounds__(256) void wt2_k(const float* __restrict__ w,
                                             __hip_bfloat16* __restrict__ wt)
{
    int idx = blockIdx.x * 256 + threadIdx.x;
    if (idx >= 128 * 576) return;
    int oc = idx / 576, k = idx % 576;
    int s = k >> 6, ic = k & 63;
    wt[idx] = __float2bfloat16(w[oc * 576 + ic * 9 + s]);
}
__global__ __launch_bounds__(256) void wt3_k(const float* __restrict__ w,
                                             __hip_bfloat16* __restrict__ wt)
{
    int idx = blockIdx.x * 256 + threadIdx.x;
    if (idx >= 128 * 1152) return;
    int oc = idx / 1152, k = idx % 1152;
    int s = k >> 7, ic = k & 127;
    wt[idx] = __float2bfloat16(w[oc * 1152 + ic * 9 + s]);
}

// conv1: d (64,1,256,128) f32 -> out NHWC (64,128,64,64) bf16. stride2 pad1.
__global__ __launch_bounds__(256) void conv1_k(
    const float* __restrict__ d, const float* __restrict__ w,
    const float* __restrict__ bias, __hip_bfloat16* __restrict__ out)
{
    __shared__ float in_s[3][66];
    __shared__ float ws_[576];
    __shared__ float bs_[64];
    int tid = threadIdx.x;
    int owhalf = blockIdx.x & 1;
    int oh = (blockIdx.x >> 1) & 127;
    int b  = blockIdx.x >> 8;
    int owbase = owhalf * 32;

    for (int l = tid; l < 576; l += 256) ws_[l] = w[l];
    if (tid < 64) bs_[tid] = bias[tid];
    for (int l = tid; l < 3 * 66; l += 256) {
        int r = l / 66, c = l % 66;
        int ih = 2 * oh - 1 + r;
        int iw = 2 * owbase - 1 + c;
        float v = 0.f;
        if ((unsigned)ih < 256u && (unsigned)iw < 128u)
            v = d[(b * 256 + ih) * 128 + iw];
        in_s[r][c] = v;
    }
    __syncthreads();

    int owl = tid >> 3, ocg = tid & 7;
    float in9[9];
#pragma unroll
    for (int r = 0; r < 3; ++r)
#pragma unroll
        for (int c = 0; c < 3; ++c)
            in9[r * 3 + c] = in_s[r][2 * owl + c];

    short8 res;
#pragma unroll
    for (int j = 0; j < 8; ++j) {
        int oc = ocg * 8 + j;
        float a = bs_[oc];
#pragma unroll
        for (int s = 0; s < 9; ++s) a = fmaf(in9[s], ws_[oc * 9 + s], a);
        union { __hip_bfloat16 h; short s; } u;
        u.h = __float2bfloat16(a);
        res[j] = u.s;
    }
    long pos = ((long)(b * 128 + oh) * 64 + owbase + owl);
    *(short8*)((short*)out + pos * 64 + ocg * 8) = res;
}

// conv2 MFMA: in NHWC (64,128,64,64) bf16 -> out NHWC (64,64,32,128) bf16
__global__ __launch_bounds__(256) void conv2_mfma(
    const __hip_bfloat16* __restrict__ in, const __hip_bfloat16* __restrict__ w2t,
    const float* __restrict__ bias, __hip_bfloat16* __restrict__ out)
{
    __shared__ short A_lds[64][32];
    __shared__ short B_lds[128][32];
    int tid = threadIdx.x;
    int oh0 = blockIdx.x * 2;
    int b   = blockIdx.y;
    int lane = tid & 63, wave = tid >> 6;
    int wr = wave >> 1, wc = wave & 1;
    floatx4 acc[2][4] = {};

    int ar = tid >> 2, aseg = tid & 3;
    int aohl = ar >> 5, aow = ar & 31;
    int boc = tid >> 2, bseg = tid & 3;

    const short* inp  = (const short*)in;
    const short* w2p  = (const short*)w2t;

    for (int s = 0; s < 9; ++s) {
        int kh = s / 3, kw = s % 3;
        int ih = 2 * (oh0 + aohl) - 1 + kh;
        int iw = 2 * aow - 1 + kw;
        bool inb = ((unsigned)ih < 128u) & ((unsigned)iw < 64u);
        const short* asrc = inp + (((b * 128 + ih) * 64 + iw) * 64 + aseg * 8);
#pragma unroll
        for (int half = 0; half < 2; ++half) {
            int koff = s * 64 + half * 32;
            short8 av = {0,0,0,0,0,0,0,0};
            if (inb) av = *(const short8*)(asrc + half * 32);
            short8 bv0 = *(const short8*)(w2p + boc * 576 + koff + bseg * 8);
            short8 bv1 = *(const short8*)(w2p + (boc + 64) * 576 + koff + bseg * 8);
            __syncthreads();
            *(short8*)&A_lds[ar][aseg * 8] = av;
            *(short8*)&B_lds[boc][bseg * 8] = bv0;
            *(short8*)&B_lds[boc + 64][bseg * 8] = bv1;
            __syncthreads();
            short8 a0 = *(const short8*)&A_lds[wr * 32 + (lane & 15)][(lane >> 4) * 8];
            short8 a1 = *(const short8*)&A_lds[wr * 32 + 16 + (lane & 15)][(lane >> 4) * 8];
#pragma unroll
            for (int ni = 0; ni < 4; ++ni) {
                short8 bv = *(const short8*)&B_lds[wc * 64 + ni * 16 + (lane & 15)][(lane >> 4) * 8];
                acc[0][ni] = __builtin_amdgcn_mfma_f32_16x16x32_bf16(a0, bv, acc[0][ni], 0, 0, 0);
                acc[1][ni] = __builtin_amdgcn_mfma_f32_16x16x32_bf16(a1, bv, acc[1][ni], 0, 0, 0);
            }
        }
    }
    float bf[4];
#pragma unroll
    for (int ni = 0; ni < 4; ++ni) bf[ni] = bias[wc * 64 + ni * 16 + (lane & 15)];
#pragma unroll
    for (int mi = 0; mi < 2; ++mi)
#pragma unroll
        for (int r = 0; r < 4; ++r) {
            int m = wr * 32 + mi * 16 + (lane >> 4) * 4 + r;
            int ohl = m >> 5, ow = m & 31;
            __hip_bfloat16* op = out + (((long)(b * 64 + oh0 + ohl) * 32) + ow) * 128;
#pragma unroll
            for (int ni = 0; ni < 4; ++ni) {
                int oc = wc * 64 + ni * 16 + (lane & 15);
                op[oc] = __float2bfloat16(acc[mi][ni][r] + bf[ni]);
            }
        }
}

// conv3 MFMA: in NHWC (64,64,32,128) bf16 -> dep (64*512, 128) fp32
__global__ __launch_bounds__(256) void conv3_mfma(
    const __hip_bfloat16* __restrict__ in, const __hip_bfloat16* __restrict__ w3t,
    const float* __restrict__ bias, float* __restrict__ dep)
{
    __shared__ short A_lds[64][32];
    __shared__ short B_lds[128][32];
    int tid = threadIdx.x;
    int oh0 = blockIdx.x * 4;
    int b   = blockIdx.y;
    int lane = tid & 63, wave = tid >> 6;
    int wr = wave >> 1, wc = wave & 1;
    floatx4 acc[2][4] = {};

    int ar = tid >> 2, aseg = tid & 3;
    int aohl = ar >> 4, aow = ar & 15;
    int boc = tid >> 2, bseg = tid & 3;

    const short* inp = (const short*)in;
    const short* w3p = (const short*)w3t;

    for (int s = 0; s < 9; ++s) {
        int kh = s / 3, kw = s % 3;
        int ih = 2 * (oh0 + aohl) - 1 + kh;
        int iw = 2 * aow - 1 + kw;
        bool inb = ((unsigned)ih < 64u) & ((unsigned)iw < 32u);
        const short* asrc = inp + (((b * 64 + ih) * 32 + iw) * 128 + aseg * 8);
#pragma unroll
        for (int q = 0; q < 4; ++q) {
            int koff = s * 128 + q * 32;
            short8 av = {0,0,0,0,0,0,0,0};
            if (inb) av = *(const short8*)(asrc + q * 32);
            short8 bv0 = *(const short8*)(w3p + boc * 1152 + koff + bseg * 8);
            short8 bv1 = *(const short8*)(w3p + (boc + 64) * 1152 + koff + bseg * 8);
            __syncthreads();
            *(short8*)&A_lds[ar][aseg * 8] = av;
            *(short8*)&B_lds[boc][bseg * 8] = bv0;
            *(short8*)&B_lds[boc + 64][bseg * 8] = bv1;
            __syncthreads();
            short8 a0 = *(const short8*)&A_lds[wr * 32 + (lane & 15)][(lane >> 4) * 8];
            short8 a1 = *(const short8*)&A_lds[wr * 32 + 16 + (lane & 15)][(lane >> 4) * 8];
#pragma unroll
            for (int ni = 0; ni < 4; ++ni) {
                short8 bv = *(const short8*)&B_lds[wc * 64 + ni * 16 + (lane & 15)][(lane >> 4) * 8];
                acc[0][ni] = __builtin_amdgcn_mfma_f32_16x16x32_bf16(a0, bv, acc[0][ni], 0, 0, 0);
                acc[1][ni] = __builtin_amdgcn_mfma_f32_16x16x32_bf16(a1, bv, acc[1][ni], 0, 0, 0);
            }
        }
    }
    float bf[4];
#pragma unroll
    for (int ni = 0; ni < 4; ++ni) bf[ni] = bias[wc * 64 + ni * 16 + (lane & 15)];
#pragma unroll
    for (int mi = 0; mi < 2; ++mi)
#pragma unroll
        for (int r = 0; r < 4; ++r) {
            int m = wr * 32 + mi * 16 + (lane >> 4) * 4 + r;
            float* op = dep + ((long)b * 512 + oh0 * 16 + m) * 128;
#pragma unroll
            for (int ni = 0; ni < 4; ++ni) {
                int oc = wc * 64 + ni * 16 + (lane & 15);
                op[oc] = acc[mi][ni][r] + bf[ni];
            }
        }
}

// v = dep @ W_mv + c0v via bf16 MFMA hi/lo split (~fp32 accuracy).
// 512 blocks x 64 rows. B-frags from L2-resident prepped [n][k] hi/lo.
__global__ __launch_bounds__(256) void vgemm_mfma(
    const float* __restrict__ dep, const __hip_bfloat16* __restrict__ Bh,
    const __hip_bfloat16* __restrict__ Bl, const float* __restrict__ c0v,
    float* __restrict__ v)
{
    __shared__ short Ah[64][136];   // pad 136: 16B-aligned rows, 2-way banks
    __shared__ short Al[64][136];
    int tid = threadIdx.x;
    int m0 = blockIdx.x * 64;

    for (int l4 = tid; l4 < 64 * 32; l4 += 256) {
        int r = l4 >> 5, c4 = l4 & 31;
        const float* sp = dep + ((long)(m0 + r) << 7) + c4 * 4;
        shortx4 hv, lv;
#pragma unroll
        for (int i = 0; i < 4; ++i) {
            float f = sp[i];
            union { __hip_bfloat16 b; short s; } uh, ul;
            uh.b = __float2bfloat16(f);
            ul.b = __float2bfloat16(f - __bfloat162float(uh.b));
            hv[i] = uh.s; lv[i] = ul.s;
        }
        *(shortx4*)&Ah[r][c4 * 4] = hv;
        *(shortx4*)&Al[r][c4 * 4] = lv;
    }
    __syncthreads();

    int lane = tid & 63, wave = tid >> 6;
    int wr = wave >> 1, wc = wave & 1;
    int l16 = lane & 15, lh = lane >> 4;
    floatx4 acc[2][4] = {};
#pragma unroll
    for (int kk = 0; kk < 4; ++kk) {
        short8 ah[2], al[2];
#pragma unroll
        for (int mi = 0; mi < 2; ++mi) {
            ah[mi] = *(const short8*)&Ah[wr * 32 + mi * 16 + l16][kk * 32 + lh * 8];
            al[mi] = *(const short8*)&Al[wr * 32 + mi * 16 + l16][kk * 32 + lh * 8];
        }
#pragma unroll
        for (int nf = 0; nf < 4; ++nf) {
            int gn = wc * 64 + nf * 16 + l16;
            short8 bh = *(const short8*)((const short*)Bh + gn * 128 + kk * 32 + lh * 8);
            short8 bl = *(const short8*)((const short*)Bl + gn * 128 + kk * 32 + lh * 8);
#pragma unroll
            for (int mi = 0; mi < 2; ++mi) {
                acc[mi][nf] = __builtin_amdgcn_mfma_f32_16x16x32_bf16(ah[mi], bh, acc[mi][nf], 0, 0, 0);
                acc[mi][nf] = __builtin_amdgcn_mfma_f32_16x16x32_bf16(al[mi], bh, acc[mi][nf], 0, 0, 0);
                acc[mi][nf] = __builtin_amdgcn_mfma_f32_16x16x32_bf16(ah[mi], bl, acc[mi][nf], 0, 0, 0);
            }
        }
    }
#pragma unroll
    for (int nf = 0; nf < 4; ++nf) {
        int gn = wc * 64 + nf * 16 + l16;
        float cv = c0v[gn];
#pragma unroll
        for (int mi = 0; mi < 2; ++mi)
#pragma unroll
            for (int r = 0; r < 4; ++r) {
                int m = m0 + wr * 32 + mi * 16 + lh * 4 + r;
                v[(long)m * 128 + gn] = acc[mi][nf][r] + cv;
            }
    }
}

// sel: fp32 GEMM (8192x72x768) + fused sigmoid + softmax -> lx/ly/attn.
// 256 blocks x 32 rows; thread=(row, jgroup of 9 outputs); K-chunks of 96.
__global__ __launch_bounds__(256) void selgemm_k(
    const float* __restrict__ F, const float* __restrict__ Wb,
    const float* __restrict__ rowbias,
    float* __restrict__ lx, float* __restrict__ ly, float* __restrict__ attn)
{
    __shared__ float As[32][97];
    __shared__ float Bs[96 * 72];
    int tid = threadIdx.x;
    int bid = blockIdx.x;
    int m0 = bid * 32;
    int padd = (bid >> 2) + 1;      // feature-row offset (constant per block)
    int rr = tid >> 3, jg = tid & 7;

    float acc[9];
#pragma unroll
    for (int jj = 0; jj < 9; ++jj)
        acc[jj] = rowbias[(bid >> 2) * 72 + jg * 9 + jj];

    for (int k0 = 0; k0 < 768; k0 += 96) {
        __syncthreads();
        for (int l = tid; l < 32 * 96; l += 256) {
            int r = l / 96, c = l - r * 96;
            As[r][c] = F[(long)(m0 + r + padd) * 768 + k0 + c];
        }
        for (int l = tid; l < 96 * 72; l += 256)
            Bs[l] = Wb[k0 * 72 + l];
        __syncthreads();
#pragma unroll 4
        for (int k = 0; k < 96; ++k) {
            float a = As[rr][k];
            const float* bp = &Bs[k * 72 + jg * 9];
#pragma unroll
            for (int jj = 0; jj < 9; ++jj)
                acc[jj] = fmaf(a, bp[jj], acc[jj]);
        }
    }
    float sig[9];
#pragma unroll
    for (int jj = 0; jj < 9; ++jj)
        sig[jj] = 1.f / (1.f + expf(-acc[jj]));
    int jbase = jg * 9;
    float lmax = -1e30f;
#pragma unroll
    for (int jj = 0; jj < 9; ++jj)
        if (jbase + jj >= 48) lmax = fmaxf(lmax, sig[jj]);
#pragma unroll
    for (int s = 1; s < 8; s <<= 1)
        lmax = fmaxf(lmax, __shfl_xor(lmax, s, 8));
    float lsum = 0.f;
#pragma unroll
    for (int jj = 0; jj < 9; ++jj)
        if (jbase + jj >= 48) lsum += expf(sig[jj] - lmax);
#pragma unroll
    for (int s = 1; s < 8; s <<= 1)
        lsum += __shfl_xor(lsum, s, 8);
    int row = m0 + rr;
#pragma unroll
    for (int jj = 0; jj < 9; ++jj) {
        int j = jbase + jj;
        if (j < 48) {
            if ((j & 1) == 0) lx[row * 24 + (j >> 1)] = sig[jj];
            else              ly[row * 24 + (j >> 1)] = sig[jj];
        } else {
            attn[row * 24 + j - 48] = expf(sig[jj] - lmax) / lsum;
        }
    }
}

// bilinear gather + attn-weighted mean over 24 keypoints
__global__ __launch_bounds__(128) void r2d_k(
    const float* __restrict__ v, const float* __restrict__ lx,
    const float* __restrict__ ly, const float* __restrict__ attn,
    float* __restrict__ r2d)
{
    int n = blockIdx.x;
    int b = blockIdx.y;
    int c = threadIdx.x;
    int row = b * 128 + n;
    __shared__ float sx[24], sy[24], sa[24];
    if (c < 24) { sx[c] = lx[row * 24 + c]; sy[c] = ly[row * 24 + c]; sa[c] = attn[row * 24 + c]; }
    __syncthreads();
    const float* vb = v + (long)b * 512 * 128;
    float acc = 0.f;
    for (int k = 0; k < 24; ++k) {
        float lxv = sx[k], lyv = sy[k], a = sa[k];
        float x1 = floorf(lxv * 15.f), x2 = fminf(x1 + 1.f, 15.f);
        float y1 = floorf(lyv * 31.f), y2 = fminf(y1 + 1.f, 31.f);
        int xi1 = (int)x1, xi2 = (int)x2, yi1 = (int)y1, yi2 = (int)y2;
        float f0 = vb[(xi1 * 16 + yi2) * 128 + c];
        float f1 = vb[(xi2 * 16 + yi2) * 128 + c];
        float f2 = vb[(xi2 * 16 + yi1) * 128 + c];
        float f3 = vb[(xi1 * 16 + yi1) * 128 + c];
        float x = lxv * 16.f, y = lyv * 32.f;
        float w_ = x2 - x1, h_ = y2 - y1;
        float hwp = h_ * w_;
        bool deg = (h_ == 0.f) || (w_ == 0.f);
        float denom = (hwp == 0.f) ? 1.f : hwp;
        float coeff = deg ? 2.f : 1.f / denom;
        float xv0 = (w_ == 0.f) ? 1.f : (x2 - x);
        float xv1 = (w_ == 0.f) ? 1.f : (x - x1);
        float yv0 = (h_ == 0.f) ? 1.f : (y2 - y);
        float yv1 = (h_ == 0.f) ? 1.f : (y - y1);
        float interp = coeff * (xv0 * (f0 * yv0 + f1 * yv1) + xv1 * (f2 * yv0 + f3 * yv1));
        acc = fmaf(interp, a, acc);
    }
    r2d[(long)row * 128 + c] = acc * (1.f / 24.f);
}

// final_embedding[b,c] = mean over n of r2d
__global__ __launch_bounds__(128) void fe_k(const float* __restrict__ r2d,
                                            float* __restrict__ fe)
{
    int b = blockIdx.x;
    int c = threadIdx.x;
    float acc = 0.f;
    for (int nn = 0; nn < 128; ++nn) acc += r2d[((long)b * 128 + nn) * 128 + c];
    fe[b * 128 + c] = acc * (1.f / 128.f);
}

// cls_score = fe @ W_cls, thread-per-output (64*751 outputs)
__global__ __launch_bounds__(256) void cls_k(
    const float* __restrict__ fe, const float* __restrict__ W_cls,
    float* __restrict__ out)
{
    int idx = blockIdx.x * 256 + threadIdx.x;
    if (idx >= 64 * 751) return;
    int m = idx / 751, n = idx - m * 751;
    const float* fr = fe + m * 128;
    float acc = 0.f;
    for (int k = 0; k < 128; ++k)
        acc = fmaf(fr[k], W_cls[k * 751 + n], acc);
    out[idx] = acc;
}

extern "C" void kernel_launch(void* const* d_in, const int* in_sizes, int n_in,
                              void* d_out, int out_size, void* d_ws, size_t ws_size,
                              hipStream_t stream)
{
    const float* features = (const float*)d_in[0];
    const float* d        = (const float*)d_in[1];
    const float* W_rg  = (const float*)d_in[2];
    const float* b_rg  = (const float*)d_in[3];
    const float* W_rl  = (const float*)d_in[4];
    const float* b_rl  = (const float*)d_in[5];
    const float* c1w   = (const float*)d_in[6];
    const float* c1b   = (const float*)d_in[7];
    const float* c2w   = (const float*)d_in[8];
    const float* c2b   = (const float*)d_in[9];
    const float* c3w   = (const float*)d_in[10];
    const float* c3b   = (const float*)d_in[11];
    const float* g_depth = (const float*)d_in[12];
    const float* W_merge = (const float*)d_in[13];
    const float* b_merge = (const float*)d_in[14];
    const float* W_q   = (const float*)d_in[15];
    const float* b_q   = (const float*)d_in[16];
    const float* W_v   = (const float*)d_in[17];
    const float* b_v   = (const float*)d_in[18];
    const float* W_sel = (const float*)d_in[19];
    const float* b_sel = (const float*)d_in[20];
    const float* W_cls = (const float*)d_in[21];
    float* out = (float*)d_out;

    char* ws = (char*)d_ws;
    __hip_bfloat16* c1 = (__hip_bfloat16*)(ws + 0);            // NHWC, ws[0 .. 67,108,864)
    float* dep    = (float*)(ws + 0);                          // 16,777,216 (c1 dead after conv2)
    float* v      = (float*)(ws + 33554432);                   // 16,777,216
    __hip_bfloat16* c2 = (__hip_bfloat16*)(ws + 67108864);     // NHWC 33,554,432
    __hip_bfloat16* w2t = (__hip_bfloat16*)(ws + 100663296);          // 147,456
    __hip_bfloat16* w3t = (__hip_bfloat16*)(ws + 100810752);          // 294,912
    // folded-weight buffers: dead gap, untouched by convs
    float* W_qs    = (float*)(ws + 101105664);                 // 73,728
    float* W_mv    = (float*)(ws + 101179392);                 // 65,536
    float* W_big   = (float*)(ws + 101244928);                 // 221,184
    float* rowbias = (float*)(ws + 101466112);                 // 18,432
    float* c0b     = (float*)(ws + 101484544);                 // 512
    float* c0v     = (float*)(ws + 101485056);                 // 512
    float* gfeat   = (float*)(ws + 101485568);                 // 32,768
    __hip_bfloat16* Wmv_bh = (__hip_bfloat16*)(ws + 101518336);  // 32,768
    __hip_bfloat16* Wmv_bl = (__hip_bfloat16*)(ws + 101551104);  // 32,768 (ends 101,583,872)
    float* lxb    = (float*)(ws + 111411200);                  // 786,432
    float* lyb    = (float*)(ws + 112197632);                  // 786,432
    float* attnb  = (float*)(ws + 112984064);                  // 786,432
    float* r2d    = (float*)(ws + 113836544);                  // 4,194,304

    float* fe = out + 64 * 751;

    // ---- prep (folded weights) ----
    prep1_k<<<329, 256, 0, stream>>>(W_q, W_sel, W_merge, W_v, g_depth, b_merge,
                                     features, W_rg, b_rg, W_qs, W_mv, c0b, gfeat);
    prep2_k<<<289, 256, 0, stream>>>(W_rl, W_qs, W_sel, b_rl, b_q, b_sel,
                                     gfeat, c0b, W_v, b_v, W_big, rowbias, c0v);
    prep3_k<<<64, 256, 0, stream>>>(W_mv, Wmv_bh, Wmv_bl);
    wt2_k<<<288, 256, 0, stream>>>(c2w, w2t);
    wt3_k<<<576, 256, 0, stream>>>(c3w, w3t);

    // ---- conv path (MFMA) ----
    conv1_k<<<16384, 256, 0, stream>>>(d, c1w, c1b, c1);
    conv2_mfma<<<dim3(32, 64), 256, 0, stream>>>(c1, w2t, c2b, c2);
    conv3_mfma<<<dim3(8, 64), 256, 0, stream>>>(c2, w3t, c3b, dep);

    // v = dep @ W_mv + c0v   (MFMA hi/lo)
    vgemm_mfma<<<512, 256, 0, stream>>>(dep, Wmv_bh, Wmv_bl, c0v, v);
    // sel (GEMM + sigmoid + softmax fused)
    selgemm_k<<<256, 256, 0, stream>>>(features, W_big, rowbias, lxb, lyb, attnb);

    // ---- fusion tail ----
    r2d_k<<<dim3(128, 64), 128, 0, stream>>>(v, lxb, lyb, attnb, r2d);
    fe_k<<<64, 128, 0, stream>>>(r2d, fe);
    cls_k<<<188, 256, 0, stream>>>(fe, W_cls, out);
}

// Round 7
// 240.309 us; speedup vs baseline: 12.2371x; 1.1775x over previous
//
#include <hip/hip_runtime.h>
#include <hip/hip_bf16.h>

// ---------------------------------------------------------------------------
// FourDNet forward. Convs = bf16 MFMA implicit GEMM (NHWC). Folded chain:
//   v   = dep @ (W_merge_bot @ W_v) + c0v            [MFMA hi/lo split]
//   sel = sigmoid(F[:,1:] @ W_big + rowbias[b])      [MFMA hi/lo + fused softmax]
// WS rule (round 4): prep/folded buffers live outside ws[0..64MB] (c1 region).
// Round 7: selgemm fp32 (90us, 1 blk/CU latency-bound) -> selmfma hi/lo MFMA
//   (512 blks, LDS traffic /16, softmax in-wave). lx/ly accuracy ok: bilinear
//   interp is continuous in lx/ly so ~1e-5 pre-sigmoid error doesn't amplify.
// ---------------------------------------------------------------------------

typedef __attribute__((ext_vector_type(8))) short short8;
typedef __attribute__((ext_vector_type(4))) short shortx4;
typedef __attribute__((ext_vector_type(4))) float floatx4;

// ---- prep1: W_qs [256][72], W_mv [128][128], c0 [128], gfeat [64][128] ----
__global__ __launch_bounds__(256) void prep1_k(
    const float* __restrict__ W_q, const float* __restrict__ W_sel,
    const float* __restrict__ W_merge, const float* __restrict__ W_v,
    const float* __restrict__ g_depth, const float* __restrict__ b_merge,
    const float* __restrict__ features, const float* __restrict__ W_rg,
    const float* __restrict__ b_rg,
    float* __restrict__ W_qs, float* __restrict__ W_mv,
    float* __restrict__ c0, float* __restrict__ gfeat)
{
    int bid = blockIdx.x, t = threadIdx.x;
    if (bid < 72) {
        int j = bid;
        float acc = 0.f;
        for (int k = 0; k < 128; ++k)
            acc = fmaf(W_q[t * 128 + k], W_sel[k * 72 + j], acc);
        W_qs[t * 72 + j] = acc;
    } else if (bid < 200) {
        int j = bid - 72;
        if (t < 128) {
            float acc = 0.f;
            for (int k = 0; k < 128; ++k)
                acc = fmaf(W_merge[(128 + t) * 128 + k], W_v[k * 128 + j], acc);
            W_mv[t * 128 + j] = acc;
        }
    } else if (bid == 200) {
        if (t < 128) {
            float acc = b_merge[t];
            for (int k = 0; k < 128; ++k)
                acc = fmaf(g_depth[k], W_merge[k * 128 + t], acc);
            c0[t] = acc;
        }
    } else {
        int j = bid - 201;
        if (t < 64) {
            float acc = b_rg[j];
            const float* fr = features + (long)t * 129 * 768;
            for (int k = 0; k < 768; ++k)
                acc = fmaf(fr[k], W_rg[k * 128 + j], acc);
            gfeat[t * 128 + j] = acc;
        }
    }
}

// ---- prep2: W_big [768][72], rowbias [64][72], c0v [128] ----
__global__ __launch_bounds__(256) void prep2_k(
    const float* __restrict__ W_rl, const float* __restrict__ W_qs,
    const float* __restrict__ W_sel, const float* __restrict__ b_rl,
    const float* __restrict__ b_q, const float* __restrict__ b_sel,
    const float* __restrict__ gfeat, const float* __restrict__ c0,
    const float* __restrict__ W_v, const float* __restrict__ b_v,
    float* __restrict__ W_big, float* __restrict__ rowbias,
    float* __restrict__ c0v)
{
    int bid = blockIdx.x, t = threadIdx.x;
    if (bid < 216) {
        int j = bid / 3;
        int i = (bid % 3) * 256 + t;
        float acc = 0.f;
        for (int k = 0; k < 128; ++k)
            acc = fmaf(W_rl[i * 128 + k], W_qs[(128 + k) * 72 + j], acc);
        W_big[i * 72 + j] = acc;
    } else if (bid < 288) {
        int j = bid - 216;
        if (t < 64) {
            float vb = b_sel[j];
            for (int k = 0; k < 128; ++k) {
                vb = fmaf(b_rl[k], W_qs[(128 + k) * 72 + j], vb);
                vb = fmaf(b_q[k], W_sel[k * 72 + j], vb);
            }
            float acc = vb;
            for (int k = 0; k < 128; ++k)
                acc = fmaf(gfeat[t * 128 + k], W_qs[k * 72 + j], acc);
            rowbias[t * 72 + j] = acc;
        }
    } else {
        if (t < 128) {
            float acc = b_v[t];
            for (int k = 0; k < 128; ++k)
                acc = fmaf(c0[k], W_v[k * 128 + t], acc);
            c0v[t] = acc;
        }
    }
}

// ---- prep3: W_mv -> B-transposed bf16 hi/lo [n][k] ----
__global__ __launch_bounds__(256) void prep3_k(
    const float* __restrict__ W_mv,
    __hip_bfloat16* __restrict__ Bh, __hip_bfloat16* __restrict__ Bl)
{
    int idx = blockIdx.x * 256 + threadIdx.x;   // 16384
    int n = idx >> 7, k = idx & 127;
    float w = W_mv[k * 128 + n];
    __hip_bfloat16 h = __float2bfloat16(w);
    Bh[idx] = h;
    Bl[idx] = __float2bfloat16(w - __bfloat162float(h));
}

// ---- prep4: W_big [768][72] -> bf16 hi/lo [80][768] (n-major, cols>=72 zero)
__global__ __launch_bounds__(256) void prep4_k(
    const float* __restrict__ W_big,
    __hip_bfloat16* __restrict__ Wbh, __hip_bfloat16* __restrict__ Wbl)
{
    int idx = blockIdx.x * 256 + threadIdx.x;   // 80*768 = 61440
    if (idx >= 80 * 768) return;
    int n = idx / 768, k = idx - n * 768;
    float w = (n < 72) ? W_big[k * 72 + n] : 0.f;
    __hip_bfloat16 h = __float2bfloat16(w);
    Wbh[idx] = h;
    Wbl[idx] = __float2bfloat16(w - __bfloat162float(h));
}

// weight transform: OIHW fp32 -> [oc][(kh*3+kw)*IC + ic] bf16
__global__ __launch_bounds__(256) void wt2_k(const float* __restrict__ w,
                                             __hip_bfloat16* __restrict__ wt)
{
    int idx = blockIdx.x * 256 + threadIdx.x;
    if (idx >= 128 * 576) return;
    int oc = idx / 576, k = idx % 576;
    int s = k >> 6, ic = k & 63;
    wt[idx] = __float2bfloat16(w[oc * 576 + ic * 9 + s]);
}
__global__ __launch_bounds__(256) void wt3_k(const float* __restrict__ w,
                                             __hip_bfloat16* __restrict__ wt)
{
    int idx = blockIdx.x * 256 + threadIdx.x;
    if (idx >= 128 * 1152) return;
    int oc = idx / 1152, k = idx % 1152;
    int s = k >> 7, ic = k & 127;
    wt[idx] = __float2bfloat16(w[oc * 1152 + ic * 9 + s]);
}

// conv1: d (64,1,256,128) f32 -> out NHWC (64,128,64,64) bf16. stride2 pad1.
__global__ __launch_bounds__(256) void conv1_k(
    const float* __restrict__ d, const float* __restrict__ w,
    const float* __restrict__ bias, __hip_bfloat16* __restrict__ out)
{
    __shared__ float in_s[3][66];
    __shared__ float ws_[576];
    __shared__ float bs_[64];
    int tid = threadIdx.x;
    int owhalf = blockIdx.x & 1;
    int oh = (blockIdx.x >> 1) & 127;
    int b  = blockIdx.x >> 8;
    int owbase = owhalf * 32;

    for (int l = tid; l < 576; l += 256) ws_[l] = w[l];
    if (tid < 64) bs_[tid] = bias[tid];
    for (int l = tid; l < 3 * 66; l += 256) {
        int r = l / 66, c = l % 66;
        int ih = 2 * oh - 1 + r;
        int iw = 2 * owbase - 1 + c;
        float v = 0.f;
        if ((unsigned)ih < 256u && (unsigned)iw < 128u)
            v = d[(b * 256 + ih) * 128 + iw];
        in_s[r][c] = v;
    }
    __syncthreads();

    int owl = tid >> 3, ocg = tid & 7;
    float in9[9];
#pragma unroll
    for (int r = 0; r < 3; ++r)
#pragma unroll
        for (int c = 0; c < 3; ++c)
            in9[r * 3 + c] = in_s[r][2 * owl + c];

    short8 res;
#pragma unroll
    for (int j = 0; j < 8; ++j) {
        int oc = ocg * 8 + j;
        float a = bs_[oc];
#pragma unroll
        for (int s = 0; s < 9; ++s) a = fmaf(in9[s], ws_[oc * 9 + s], a);
        union { __hip_bfloat16 h; short s; } u;
        u.h = __float2bfloat16(a);
        res[j] = u.s;
    }
    long pos = ((long)(b * 128 + oh) * 64 + owbase + owl);
    *(short8*)((short*)out + pos * 64 + ocg * 8) = res;
}

// conv2 MFMA: in NHWC (64,128,64,64) bf16 -> out NHWC (64,64,32,128) bf16
__global__ __launch_bounds__(256) void conv2_mfma(
    const __hip_bfloat16* __restrict__ in, const __hip_bfloat16* __restrict__ w2t,
    const float* __restrict__ bias, __hip_bfloat16* __restrict__ out)
{
    __shared__ short A_lds[64][32];
    __shared__ short B_lds[128][32];
    int tid = threadIdx.x;
    int oh0 = blockIdx.x * 2;
    int b   = blockIdx.y;
    int lane = tid & 63, wave = tid >> 6;
    int wr = wave >> 1, wc = wave & 1;
    floatx4 acc[2][4] = {};

    int ar = tid >> 2, aseg = tid & 3;
    int aohl = ar >> 5, aow = ar & 31;
    int boc = tid >> 2, bseg = tid & 3;

    const short* inp  = (const short*)in;
    const short* w2p  = (const short*)w2t;

    for (int s = 0; s < 9; ++s) {
        int kh = s / 3, kw = s % 3;
        int ih = 2 * (oh0 + aohl) - 1 + kh;
        int iw = 2 * aow - 1 + kw;
        bool inb = ((unsigned)ih < 128u) & ((unsigned)iw < 64u);
        const short* asrc = inp + (((b * 128 + ih) * 64 + iw) * 64 + aseg * 8);
#pragma unroll
        for (int half = 0; half < 2; ++half) {
            int koff = s * 64 + half * 32;
            short8 av = {0,0,0,0,0,0,0,0};
            if (inb) av = *(const short8*)(asrc + half * 32);
            short8 bv0 = *(const short8*)(w2p + boc * 576 + koff + bseg * 8);
            short8 bv1 = *(const short8*)(w2p + (boc + 64) * 576 + koff + bseg * 8);
            __syncthreads();
            *(short8*)&A_lds[ar][aseg * 8] = av;
            *(short8*)&B_lds[boc][bseg * 8] = bv0;
            *(short8*)&B_lds[boc + 64][bseg * 8] = bv1;
            __syncthreads();
            short8 a0 = *(const short8*)&A_lds[wr * 32 + (lane & 15)][(lane >> 4) * 8];
            short8 a1 = *(const short8*)&A_lds[wr * 32 + 16 + (lane & 15)][(lane >> 4) * 8];
#pragma unroll
            for (int ni = 0; ni < 4; ++ni) {
                short8 bv = *(const short8*)&B_lds[wc * 64 + ni * 16 + (lane & 15)][(lane >> 4) * 8];
                acc[0][ni] = __builtin_amdgcn_mfma_f32_16x16x32_bf16(a0, bv, acc[0][ni], 0, 0, 0);
                acc[1][ni] = __builtin_amdgcn_mfma_f32_16x16x32_bf16(a1, bv, acc[1][ni], 0, 0, 0);
            }
        }
    }
    float bf[4];
#pragma unroll
    for (int ni = 0; ni < 4; ++ni) bf[ni] = bias[wc * 64 + ni * 16 + (lane & 15)];
#pragma unroll
    for (int mi = 0; mi < 2; ++mi)
#pragma unroll
        for (int r = 0; r < 4; ++r) {
            int m = wr * 32 + mi * 16 + (lane >> 4) * 4 + r;
            int ohl = m >> 5, ow = m & 31;
            __hip_bfloat16* op = out + (((long)(b * 64 + oh0 + ohl) * 32) + ow) * 128;
#pragma unroll
            for (int ni = 0; ni < 4; ++ni) {
                int oc = wc * 64 + ni * 16 + (lane & 15);
                op[oc] = __float2bfloat16(acc[mi][ni][r] + bf[ni]);
            }
        }
}

// conv3 MFMA: in NHWC (64,64,32,128) bf16 -> dep (64*512, 128) fp32
__global__ __launch_bounds__(256) void conv3_mfma(
    const __hip_bfloat16* __restrict__ in, const __hip_bfloat16* __restrict__ w3t,
    const float* __restrict__ bias, float* __restrict__ dep)
{
    __shared__ short A_lds[64][32];
    __shared__ short B_lds[128][32];
    int tid = threadIdx.x;
    int oh0 = blockIdx.x * 4;
    int b   = blockIdx.y;
    int lane = tid & 63, wave = tid >> 6;
    int wr = wave >> 1, wc = wave & 1;
    floatx4 acc[2][4] = {};

    int ar = tid >> 2, aseg = tid & 3;
    int aohl = ar >> 4, aow = ar & 15;
    int boc = tid >> 2, bseg = tid & 3;

    const short* inp = (const short*)in;
    const short* w3p = (const short*)w3t;

    for (int s = 0; s < 9; ++s) {
        int kh = s / 3, kw = s % 3;
        int ih = 2 * (oh0 + aohl) - 1 + kh;
        int iw = 2 * aow - 1 + kw;
        bool inb = ((unsigned)ih < 64u) & ((unsigned)iw < 32u);
        const short* asrc = inp + (((b * 64 + ih) * 32 + iw) * 128 + aseg * 8);
#pragma unroll
        for (int q = 0; q < 4; ++q) {
            int koff = s * 128 + q * 32;
            short8 av = {0,0,0,0,0,0,0,0};
            if (inb) av = *(const short8*)(asrc + q * 32);
            short8 bv0 = *(const short8*)(w3p + boc * 1152 + koff + bseg * 8);
            short8 bv1 = *(const short8*)(w3p + (boc + 64) * 1152 + koff + bseg * 8);
            __syncthreads();
            *(short8*)&A_lds[ar][aseg * 8] = av;
            *(short8*)&B_lds[boc][bseg * 8] = bv0;
            *(short8*)&B_lds[boc + 64][bseg * 8] = bv1;
            __syncthreads();
            short8 a0 = *(const short8*)&A_lds[wr * 32 + (lane & 15)][(lane >> 4) * 8];
            short8 a1 = *(const short8*)&A_lds[wr * 32 + 16 + (lane & 15)][(lane >> 4) * 8];
#pragma unroll
            for (int ni = 0; ni < 4; ++ni) {
                short8 bv = *(const short8*)&B_lds[wc * 64 + ni * 16 + (lane & 15)][(lane >> 4) * 8];
                acc[0][ni] = __builtin_amdgcn_mfma_f32_16x16x32_bf16(a0, bv, acc[0][ni], 0, 0, 0);
                acc[1][ni] = __builtin_amdgcn_mfma_f32_16x16x32_bf16(a1, bv, acc[1][ni], 0, 0, 0);
            }
        }
    }
    float bf[4];
#pragma unroll
    for (int ni = 0; ni < 4; ++ni) bf[ni] = bias[wc * 64 + ni * 16 + (lane & 15)];
#pragma unroll
    for (int mi = 0; mi < 2; ++mi)
#pragma unroll
        for (int r = 0; r < 4; ++r) {
            int m = wr * 32 + mi * 16 + (lane >> 4) * 4 + r;
            float* op = dep + ((long)b * 512 + oh0 * 16 + m) * 128;
#pragma unroll
            for (int ni = 0; ni < 4; ++ni) {
                int oc = wc * 64 + ni * 16 + (lane & 15);
                op[oc] = acc[mi][ni][r] + bf[ni];
            }
        }
}

// v = dep @ W_mv + c0v via bf16 MFMA hi/lo split (~fp32 accuracy).
__global__ __launch_bounds__(256) void vgemm_mfma(
    const float* __restrict__ dep, const __hip_bfloat16* __restrict__ Bh,
    const __hip_bfloat16* __restrict__ Bl, const float* __restrict__ c0v,
    float* __restrict__ v)
{
    __shared__ short Ah[64][136];
    __shared__ short Al[64][136];
    int tid = threadIdx.x;
    int m0 = blockIdx.x * 64;

    for (int l4 = tid; l4 < 64 * 32; l4 += 256) {
        int r = l4 >> 5, c4 = l4 & 31;
        const float* sp = dep + ((long)(m0 + r) << 7) + c4 * 4;
        shortx4 hv, lv;
#pragma unroll
        for (int i = 0; i < 4; ++i) {
            float f = sp[i];
            union { __hip_bfloat16 b; short s; } uh, ul;
            uh.b = __float2bfloat16(f);
            ul.b = __float2bfloat16(f - __bfloat162float(uh.b));
            hv[i] = uh.s; lv[i] = ul.s;
        }
        *(shortx4*)&Ah[r][c4 * 4] = hv;
        *(shortx4*)&Al[r][c4 * 4] = lv;
    }
    __syncthreads();

    int lane = tid & 63, wave = tid >> 6;
    int wr = wave >> 1, wc = wave & 1;
    int l16 = lane & 15, lh = lane >> 4;
    floatx4 acc[2][4] = {};
#pragma unroll
    for (int kk = 0; kk < 4; ++kk) {
        short8 ah[2], al[2];
#pragma unroll
        for (int mi = 0; mi < 2; ++mi) {
            ah[mi] = *(const short8*)&Ah[wr * 32 + mi * 16 + l16][kk * 32 + lh * 8];
            al[mi] = *(const short8*)&Al[wr * 32 + mi * 16 + l16][kk * 32 + lh * 8];
        }
#pragma unroll
        for (int nf = 0; nf < 4; ++nf) {
            int gn = wc * 64 + nf * 16 + l16;
            short8 bh = *(const short8*)((const short*)Bh + gn * 128 + kk * 32 + lh * 8);
            short8 bl = *(const short8*)((const short*)Bl + gn * 128 + kk * 32 + lh * 8);
#pragma unroll
            for (int mi = 0; mi < 2; ++mi) {
                acc[mi][nf] = __builtin_amdgcn_mfma_f32_16x16x32_bf16(ah[mi], bh, acc[mi][nf], 0, 0, 0);
                acc[mi][nf] = __builtin_amdgcn_mfma_f32_16x16x32_bf16(al[mi], bh, acc[mi][nf], 0, 0, 0);
                acc[mi][nf] = __builtin_amdgcn_mfma_f32_16x16x32_bf16(ah[mi], bl, acc[mi][nf], 0, 0, 0);
            }
        }
    }
#pragma unroll
    for (int nf = 0; nf < 4; ++nf) {
        int gn = wc * 64 + nf * 16 + l16;
        float cv = c0v[gn];
#pragma unroll
        for (int mi = 0; mi < 2; ++mi)
#pragma unroll
            for (int r = 0; r < 4; ++r) {
                int m = m0 + wr * 32 + mi * 16 + lh * 4 + r;
                v[(long)m * 128 + gn] = acc[mi][nf][r] + cv;
            }
    }
}

// sel: MFMA hi/lo GEMM (8192 x 80pad x 768) + fused sigmoid + softmax.
// 512 blocks x 16 rows; 4 waves: w0/w1/w2 -> nf0/1/2 (lx/ly), w3 -> nf3+nf4 (attn).
__global__ __launch_bounds__(256) void selmfma_k(
    const float* __restrict__ F, const __hip_bfloat16* __restrict__ Wbh,
    const __hip_bfloat16* __restrict__ Wbl, const float* __restrict__ rowbias,
    float* __restrict__ lx, float* __restrict__ ly, float* __restrict__ attn)
{
    __shared__ short Ah[16][136];   // pad 136: row stride 272B -> 2-way banks only
    __shared__ short Al[16][136];
    int tid = threadIdx.x;
    int m0 = blockIdx.x * 16;
    int padd = (m0 >> 7) + 1;       // feature-row offset (b const per 16-row block)
    int lane = tid & 63, wave = tid >> 6;
    int l16 = lane & 15, lh = lane >> 4;

    int sr = tid >> 4, sc = (tid & 15) * 8;   // stage: row, 8-k chunk
    const float* fsrc = F + (long)(m0 + sr + padd) * 768 + sc;

    floatx4 acc0 = {0.f, 0.f, 0.f, 0.f};
    floatx4 acc1 = {0.f, 0.f, 0.f, 0.f};
    bool two = (wave == 3);
    const short* bhp = (const short*)Wbh;
    const short* blp = (const short*)Wbl;
    int gn0 = wave * 16 + l16;      // nf = wave for tile 0
    int gn1 = 64 + l16;             // nf = 4 (wave 3 only)

    for (int c = 0; c < 6; ++c) {
        __syncthreads();
        float4 f0 = *(const float4*)(fsrc + c * 128);
        float4 f1 = *(const float4*)(fsrc + c * 128 + 4);
        shortx4 h0, l0, h1, l1;
#pragma unroll
        for (int i = 0; i < 4; ++i) {
            union { __hip_bfloat16 b; short s; } uh, ul;
            float fa = (&f0.x)[i];
            uh.b = __float2bfloat16(fa);
            ul.b = __float2bfloat16(fa - __bfloat162float(uh.b));
            h0[i] = uh.s; l0[i] = ul.s;
            float fb = (&f1.x)[i];
            uh.b = __float2bfloat16(fb);
            ul.b = __float2bfloat16(fb - __bfloat162float(uh.b));
            h1[i] = uh.s; l1[i] = ul.s;
        }
        *(shortx4*)&Ah[sr][sc]     = h0;
        *(shortx4*)&Ah[sr][sc + 4] = h1;
        *(shortx4*)&Al[sr][sc]     = l0;
        *(shortx4*)&Al[sr][sc + 4] = l1;
        __syncthreads();
#pragma unroll
        for (int ks = 0; ks < 4; ++ks) {
            short8 ah = *(const short8*)&Ah[l16][ks * 32 + lh * 8];
            short8 al = *(const short8*)&Al[l16][ks * 32 + lh * 8];
            int koff = c * 128 + ks * 32 + lh * 8;
            short8 bh0 = *(const short8*)(bhp + gn0 * 768 + koff);
            short8 bl0 = *(const short8*)(blp + gn0 * 768 + koff);
            acc0 = __builtin_amdgcn_mfma_f32_16x16x32_bf16(ah, bh0, acc0, 0, 0, 0);
            acc0 = __builtin_amdgcn_mfma_f32_16x16x32_bf16(al, bh0, acc0, 0, 0, 0);
            acc0 = __builtin_amdgcn_mfma_f32_16x16x32_bf16(ah, bl0, acc0, 0, 0, 0);
            if (two) {
                short8 bh1 = *(const short8*)(bhp + gn1 * 768 + koff);
                short8 bl1 = *(const short8*)(blp + gn1 * 768 + koff);
                acc1 = __builtin_amdgcn_mfma_f32_16x16x32_bf16(ah, bh1, acc1, 0, 0, 0);
                acc1 = __builtin_amdgcn_mfma_f32_16x16x32_bf16(al, bh1, acc1, 0, 0, 0);
                acc1 = __builtin_amdgcn_mfma_f32_16x16x32_bf16(ah, bl1, acc1, 0, 0, 0);
            }
        }
    }

    // epilogue: C row = lh*4+r (m), col = l16 (n)
    if (wave < 3) {
        int j = wave * 16 + l16;    // j < 48
#pragma unroll
        for (int r = 0; r < 4; ++r) {
            int row = m0 + lh * 4 + r;
            float val = acc0[r] + rowbias[(row >> 7) * 72 + j];
            float sg = 1.f / (1.f + expf(-val));
            if (j & 1) ly[row * 24 + (j >> 1)] = sg;
            else       lx[row * 24 + (j >> 1)] = sg;
        }
    } else {
#pragma unroll
        for (int r = 0; r < 4; ++r) {
            int row = m0 + lh * 4 + r;
            int b72 = (row >> 7) * 72;
            float s0 = 1.f / (1.f + expf(-(acc0[r] + rowbias[b72 + 48 + l16])));
            float s1 = -1e30f;
            if (l16 < 8)
                s1 = 1.f / (1.f + expf(-(acc1[r] + rowbias[b72 + 64 + l16])));
            float mx = fmaxf(s0, s1);
#pragma unroll
            for (int s = 1; s < 16; s <<= 1)
                mx = fmaxf(mx, __shfl_xor(mx, s));
            float e0 = expf(s0 - mx);
            float e1 = (l16 < 8) ? expf(s1 - mx) : 0.f;
            float sum = e0 + e1;
#pragma unroll
            for (int s = 1; s < 16; s <<= 1)
                sum += __shfl_xor(sum, s);
            attn[row * 24 + l16] = e0 / sum;
            if (l16 < 8) attn[row * 24 + 16 + l16] = e1 / sum;
        }
    }
}

// bilinear gather + attn-weighted mean over 24 keypoints
__global__ __launch_bounds__(128) void r2d_k(
    const float* __restrict__ v, const float* __restrict__ lx,
    const float* __restrict__ ly, const float* __restrict__ attn,
    float* __restrict__ r2d)
{
    int n = blockIdx.x;
    int b = blockIdx.y;
    int c = threadIdx.x;
    int row = b * 128 + n;
    __shared__ float sx[24], sy[24], sa[24];
    if (c < 24) { sx[c] = lx[row * 24 + c]; sy[c] = ly[row * 24 + c]; sa[c] = attn[row * 24 + c]; }
    __syncthreads();
    const float* vb = v + (long)b * 512 * 128;
    float acc = 0.f;
    for (int k = 0; k < 24; ++k) {
        float lxv = sx[k], lyv = sy[k], a = sa[k];
        float x1 = floorf(lxv * 15.f), x2 = fminf(x1 + 1.f, 15.f);
        float y1 = floorf(lyv * 31.f), y2 = fminf(y1 + 1.f, 31.f);
        int xi1 = (int)x1, xi2 = (int)x2, yi1 = (int)y1, yi2 = (int)y2;
        float f0 = vb[(xi1 * 16 + yi2) * 128 + c];
        float f1 = vb[(xi2 * 16 + yi2) * 128 + c];
        float f2 = vb[(xi2 * 16 + yi1) * 128 + c];
        float f3 = vb[(xi1 * 16 + yi1) * 128 + c];
        float x = lxv * 16.f, y = lyv * 32.f;
        float w_ = x2 - x1, h_ = y2 - y1;
        float hwp = h_ * w_;
        bool deg = (h_ == 0.f) || (w_ == 0.f);
        float denom = (hwp == 0.f) ? 1.f : hwp;
        float coeff = deg ? 2.f : 1.f / denom;
        float xv0 = (w_ == 0.f) ? 1.f : (x2 - x);
        float xv1 = (w_ == 0.f) ? 1.f : (x - x1);
        float yv0 = (h_ == 0.f) ? 1.f : (y2 - y);
        float yv1 = (h_ == 0.f) ? 1.f : (y - y1);
        float interp = coeff * (xv0 * (f0 * yv0 + f1 * yv1) + xv1 * (f2 * yv0 + f3 * yv1));
        acc = fmaf(interp, a, acc);
    }
    r2d[(long)row * 128 + c] = acc * (1.f / 24.f);
}

// final_embedding[b,c] = mean over n of r2d
__global__ __launch_bounds__(128) void fe_k(const float* __restrict__ r2d,
                                            float* __restrict__ fe)
{
    int b = blockIdx.x;
    int c = threadIdx.x;
    float acc = 0.f;
    for (int nn = 0; nn < 128; ++nn) acc += r2d[((long)b * 128 + nn) * 128 + c];
    fe[b * 128 + c] = acc * (1.f / 128.f);
}

// cls_score = fe @ W_cls, thread-per-output
__global__ __launch_bounds__(256) void cls_k(
    const float* __restrict__ fe, const float* __restrict__ W_cls,
    float* __restrict__ out)
{
    int idx = blockIdx.x * 256 + threadIdx.x;
    if (idx >= 64 * 751) return;
    int m = idx / 751, n = idx - m * 751;
    const float* fr = fe + m * 128;
    float acc = 0.f;
    for (int k = 0; k < 128; ++k)
        acc = fmaf(fr[k], W_cls[k * 751 + n], acc);
    out[idx] = acc;
}

extern "C" void kernel_launch(void* const* d_in, const int* in_sizes, int n_in,
                              void* d_out, int out_size, void* d_ws, size_t ws_size,
                              hipStream_t stream)
{
    const float* features = (const float*)d_in[0];
    const float* d        = (const float*)d_in[1];
    const float* W_rg  = (const float*)d_in[2];
    const float* b_rg  = (const float*)d_in[3];
    const float* W_rl  = (const float*)d_in[4];
    const float* b_rl  = (const float*)d_in[5];
    const float* c1w   = (const float*)d_in[6];
    const float* c1b   = (const float*)d_in[7];
    const float* c2w   = (const float*)d_in[8];
    const float* c2b   = (const float*)d_in[9];
    const float* c3w   = (const float*)d_in[10];
    const float* c3b   = (const float*)d_in[11];
    const float* g_depth = (const float*)d_in[12];
    const float* W_merge = (const float*)d_in[13];
    const float* b_merge = (const float*)d_in[14];
    const float* W_q   = (const float*)d_in[15];
    const float* b_q   = (const float*)d_in[16];
    const float* W_v   = (const float*)d_in[17];
    const float* b_v   = (const float*)d_in[18];
    const float* W_sel = (const float*)d_in[19];
    const float* b_sel = (const float*)d_in[20];
    const float* W_cls = (const float*)d_in[21];
    float* out = (float*)d_out;

    char* ws = (char*)d_ws;
    __hip_bfloat16* c1 = (__hip_bfloat16*)(ws + 0);            // NHWC, ws[0 .. 67,108,864)
    float* dep    = (float*)(ws + 0);                          // 16,777,216 (c1 dead after conv2)
    float* v      = (float*)(ws + 33554432);                   // 16,777,216
    __hip_bfloat16* c2 = (__hip_bfloat16*)(ws + 67108864);     // NHWC 33,554,432
    __hip_bfloat16* w2t = (__hip_bfloat16*)(ws + 100663296);          // 147,456
    __hip_bfloat16* w3t = (__hip_bfloat16*)(ws + 100810752);          // 294,912
    // folded-weight buffers: dead gap, untouched by convs
    float* W_qs    = (float*)(ws + 101105664);                 // 73,728
    float* W_mv    = (float*)(ws + 101179392);                 // 65,536
    float* W_big   = (float*)(ws + 101244928);                 // 221,184
    float* rowbias = (float*)(ws + 101466112);                 // 18,432
    float* c0b     = (float*)(ws + 101484544);                 // 512
    float* c0v     = (float*)(ws + 101485056);                 // 512
    float* gfeat   = (float*)(ws + 101485568);                 // 32,768
    __hip_bfloat16* Wmv_bh = (__hip_bfloat16*)(ws + 101518336);  // 32,768
    __hip_bfloat16* Wmv_bl = (__hip_bfloat16*)(ws + 101551104);  // 32,768
    __hip_bfloat16* Wbig_h = (__hip_bfloat16*)(ws + 101583872);  // 122,880
    __hip_bfloat16* Wbig_l = (__hip_bfloat16*)(ws + 101706752);  // 122,880 (ends 101,829,632)
    float* lxb    = (float*)(ws + 111411200);                  // 786,432
    float* lyb    = (float*)(ws + 112197632);                  // 786,432
    float* attnb  = (float*)(ws + 112984064);                  // 786,432
    float* r2d    = (float*)(ws + 113836544);                  // 4,194,304

    float* fe = out + 64 * 751;

    // ---- prep (folded weights) ----
    prep1_k<<<329, 256, 0, stream>>>(W_q, W_sel, W_merge, W_v, g_depth, b_merge,
                                     features, W_rg, b_rg, W_qs, W_mv, c0b, gfeat);
    prep2_k<<<289, 256, 0, stream>>>(W_rl, W_qs, W_sel, b_rl, b_q, b_sel,
                                     gfeat, c0b, W_v, b_v, W_big, rowbias, c0v);
    prep3_k<<<64, 256, 0, stream>>>(W_mv, Wmv_bh, Wmv_bl);
    prep4_k<<<240, 256, 0, stream>>>(W_big, Wbig_h, Wbig_l);
    wt2_k<<<288, 256, 0, stream>>>(c2w, w2t);
    wt3_k<<<576, 256, 0, stream>>>(c3w, w3t);

    // ---- conv path (MFMA) ----
    conv1_k<<<16384, 256, 0, stream>>>(d, c1w, c1b, c1);
    conv2_mfma<<<dim3(32, 64), 256, 0, stream>>>(c1, w2t, c2b, c2);
    conv3_mfma<<<dim3(8, 64), 256, 0, stream>>>(c2, w3t, c3b, dep);

    // v = dep @ W_mv + c0v   (MFMA hi/lo)
    vgemm_mfma<<<512, 256, 0, stream>>>(dep, Wmv_bh, Wmv_bl, c0v, v);
    // sel (MFMA hi/lo GEMM + sigmoid + softmax fused)
    selmfma_k<<<512, 256, 0, stream>>>(features, Wbig_h, Wbig_l, rowbias,
                                       lxb, lyb, attnb);

    // ---- fusion tail ----
    r2d_k<<<dim3(128, 64), 128, 0, stream>>>(v, lxb, lyb, attnb, r2d);
    fe_k<<<64, 128, 0, stream>>>(r2d, fe);
    cls_k<<<188, 256, 0, stream>>>(fe, W_cls, out);
}